// Round 5
// baseline (2797.779 us; speedup 1.0000x reference)
//
#include <hip/hip_runtime.h>

#define N_ 1024
#define D_ 128
#define K_ 256
#define M_ 4
#define H_ 256
#define NB_ 2
#define KT_ 32
#define EPS_ 0.35f
#define CHPAD 136
#define HPAD 264

typedef __attribute__((ext_vector_type(8))) short short8;
typedef __attribute__((ext_vector_type(4))) float f32x4;

__device__ inline unsigned short f32_to_bf16_rne(float x) {
    unsigned u = __float_as_uint(x);
    unsigned r = u + 0x7FFFu + ((u >> 16) & 1u);
    return (unsigned short)(r >> 16);
}
__device__ inline void split2(float x, unsigned short& hi, unsigned short& lo) {
    unsigned u = __float_as_uint(x) & 0xFFFF0000u;
    hi = (unsigned short)(u >> 16);
    lo = f32_to_bf16_rne(x - __uint_as_float(u));
}
__device__ inline float bf2f(unsigned short h) {
    return __uint_as_float(((unsigned)h) << 16);
}

// ---------------------------------------------------------------------------
// Bb[m,k,d] = f32( exact_sum_d' cb[k,d'] * cp_w[m,d,D+d'] )   (B only)
// ---------------------------------------------------------------------------
__global__ void precompute_Bb(const float* __restrict__ base_cb,
                              const float* __restrict__ cp_w,
                              float* __restrict__ Bb) {
    const int mk = blockIdx.x;
    const int m  = mk >> 8;
    const int d  = threadIdx.x;
    const float* cb = base_cb + (size_t)mk * D_;
    const float* wc = cp_w + ((size_t)(m * D_ + d)) * (2 * D_) + D_;
    double a0 = 0, a1 = 0, a2 = 0, a3 = 0;
    #pragma unroll
    for (int dp = 0; dp < D_; dp += 4) {
        a0 += (double)(cb[dp + 0] * wc[dp + 0]);
        a1 += (double)(cb[dp + 1] * wc[dp + 1]);
        a2 += (double)(cb[dp + 2] * wc[dp + 2]);
        a3 += (double)(cb[dp + 3] * wc[dp + 3]);
    }
    Bb[(size_t)mk * D_ + d] = (float)((a0 + a1) + (a2 + a3));
}

__global__ void convert_w(const float* __restrict__ w1,
                          const float* __restrict__ w2,
                          unsigned short* __restrict__ w1h,
                          unsigned short* __restrict__ w1l,
                          unsigned short* __restrict__ w2h,
                          unsigned short* __restrict__ w2l) {
    const int i = blockIdx.x * blockDim.x + threadIdx.x;
    unsigned short h, l;
    split2(w1[i], h, l); w1h[i] = h; w1l[i] = l;
    split2(w2[i], h, l); w2h[i] = h; w2l[i] = l;
}

__global__ void init_state(float* __restrict__ xhat, float* __restrict__ Ag) {
    const int i = blockIdx.x * blockDim.x + threadIdx.x;  // 0..131071
    xhat[i] = 0.0f;
    Ag[i] = 0.0f;
}

// ---------------------------------------------------------------------------
// dist kernel: grid = N*8; block (n, kt) computes fast dists for 32 codewords.
// ---------------------------------------------------------------------------
__launch_bounds__(256, 2)
__global__ void dist_kernel(const int m,
                            const float* __restrict__ z,
                            const float* __restrict__ cp_b,
                            const float* __restrict__ xhat,
                            const float* __restrict__ Ag,
                            const float* __restrict__ Bb,
                            const unsigned short* __restrict__ w1hi,
                            const unsigned short* __restrict__ w1lo,
                            const unsigned short* __restrict__ w2hi,
                            const unsigned short* __restrict__ w2lo,
                            const float* __restrict__ b1,
                            const float* __restrict__ b2,
                            float* __restrict__ gdist) {
    __shared__ alignas(16) unsigned short sChi[KT_][CHPAD];
    __shared__ alignas(16) unsigned short sClo[KT_][CHPAD];
    __shared__ alignas(16) unsigned short sHhi[KT_][HPAD];
    __shared__ alignas(16) unsigned short sHlo[KT_][HPAD];
    __shared__ float sA[D_], sr[D_], scb[D_];

    const int bid  = blockIdx.x;
    const int n    = bid >> 3;
    const int k0   = (bid & 7) * KT_;
    const int t    = threadIdx.x;
    const int wid  = t >> 6;
    const int lane = t & 63;
    const int l15  = lane & 15;
    const int q    = lane >> 4;

    if (t < D_) {
        sA[t]  = Ag[(size_t)n * D_ + t];
        sr[t]  = z[(size_t)n * D_ + t] - xhat[(size_t)n * D_ + t];
        scb[t] = cp_b[m * D_ + t];
    }
    __syncthreads();

    // ---- C init: C = (A + Bb) + cp_b, split to bf16 hi/lo, b128 stores ----
    {
        const int row  = t >> 3;
        const int dblk = (t & 7) * 16;
        const f32x4* bb4 = (const f32x4*)(Bb + ((size_t)(m * K_ + k0 + row)) * D_ + dblk);
        #pragma unroll
        for (int g = 0; g < 2; ++g) {
            const f32x4 v0 = bb4[g * 2];
            const f32x4 v1 = bb4[g * 2 + 1];
            short8 hs, ls;
            #pragma unroll
            for (int x = 0; x < 8; ++x) {
                const int d = dblk + g * 8 + x;
                const float bv = (x < 4) ? v0[x] : v1[x - 4];
                const float cv = (sA[d] + bv) + scb[d];
                unsigned short ch, cl;
                split2(cv, ch, cl);
                hs[x] = (short)ch;
                ls[x] = (short)cl;
            }
            *(short8*)&sChi[row][dblk + g * 8] = hs;
            *(short8*)&sClo[row][dblk + g * 8] = ls;
        }
    }
    __syncthreads();

    for (int i = 0; i < NB_; ++i) {
        const int bi = m * NB_ + i;

        // ---- GEMM1: h = relu(C @ W1^T + b1), bf16 3-pass split ----
        {
            const unsigned short* w1h = w1hi + (size_t)bi * H_ * D_;
            const unsigned short* w1l = w1lo + (size_t)bi * H_ * D_;
            #pragma unroll
            for (int u = 0; u < 4; ++u) {
                const int jcol = (wid * 4 + u) * 16 + l15;
                const size_t wbase = (size_t)jcol * D_ + q * 8;
                short8 bh[4], bl[4];
                #pragma unroll
                for (int kk = 0; kk < 4; ++kk) {
                    bh[kk] = *(const short8*)(w1h + wbase + kk * 32);
                    bl[kk] = *(const short8*)(w1l + wbase + kk * 32);
                }
                const float b1v = b1[(size_t)bi * H_ + jcol];
                #pragma unroll
                for (int mt = 0; mt < 2; ++mt) {
                    const int r = mt * 16 + l15;
                    f32x4 acc = {0.f, 0.f, 0.f, 0.f};
                    #pragma unroll
                    for (int kk = 0; kk < 4; ++kk) {
                        short8 ah = *(const short8*)&sChi[r][kk * 32 + q * 8];
                        short8 al = *(const short8*)&sClo[r][kk * 32 + q * 8];
                        acc = __builtin_amdgcn_mfma_f32_16x16x32_bf16(ah, bh[kk], acc, 0, 0, 0);
                        acc = __builtin_amdgcn_mfma_f32_16x16x32_bf16(ah, bl[kk], acc, 0, 0, 0);
                        acc = __builtin_amdgcn_mfma_f32_16x16x32_bf16(al, bh[kk], acc, 0, 0, 0);
                    }
                    #pragma unroll
                    for (int qq = 0; qq < 4; ++qq) {
                        const float hv = fmaxf(acc[qq] + b1v, 0.0f);
                        unsigned short hh, hl;
                        split2(hv, hh, hl);
                        sHhi[mt * 16 + q * 4 + qq][jcol] = hh;
                        sHlo[mt * 16 + q * 4 + qq][jcol] = hl;
                    }
                }
            }
        }
        __syncthreads();

        // ---- GEMM2: C = (C + h @ W2^T) + b2 ----
        {
            const unsigned short* w2h = w2hi + (size_t)bi * D_ * H_;
            const unsigned short* w2l = w2lo + (size_t)bi * D_ * H_;
            #pragma unroll
            for (int u = 0; u < 2; ++u) {
                const int dcol = (wid * 2 + u) * 16 + l15;
                const float b2v = b2[(size_t)bi * D_ + dcol];
                const size_t wbase = (size_t)dcol * H_ + q * 8;
                f32x4 acc0 = {0.f, 0.f, 0.f, 0.f};
                f32x4 acc1 = {0.f, 0.f, 0.f, 0.f};
                #pragma unroll
                for (int kk = 0; kk < 8; ++kk) {
                    short8 bh = *(const short8*)(w2h + wbase + kk * 32);
                    short8 bl = *(const short8*)(w2l + wbase + kk * 32);
                    short8 ah0 = *(const short8*)&sHhi[l15][kk * 32 + q * 8];
                    short8 al0 = *(const short8*)&sHlo[l15][kk * 32 + q * 8];
                    acc0 = __builtin_amdgcn_mfma_f32_16x16x32_bf16(ah0, bh, acc0, 0, 0, 0);
                    acc0 = __builtin_amdgcn_mfma_f32_16x16x32_bf16(ah0, bl, acc0, 0, 0, 0);
                    acc0 = __builtin_amdgcn_mfma_f32_16x16x32_bf16(al0, bh, acc0, 0, 0, 0);
                    short8 ah1 = *(const short8*)&sHhi[16 + l15][kk * 32 + q * 8];
                    short8 al1 = *(const short8*)&sHlo[16 + l15][kk * 32 + q * 8];
                    acc1 = __builtin_amdgcn_mfma_f32_16x16x32_bf16(ah1, bh, acc1, 0, 0, 0);
                    acc1 = __builtin_amdgcn_mfma_f32_16x16x32_bf16(ah1, bl, acc1, 0, 0, 0);
                    acc1 = __builtin_amdgcn_mfma_f32_16x16x32_bf16(al1, bh, acc1, 0, 0, 0);
                }
                #pragma unroll
                for (int qq = 0; qq < 4; ++qq) {
                    const int r = q * 4 + qq;
                    const float cvo = bf2f(sChi[r][dcol]) + bf2f(sClo[r][dcol]);
                    const float cv = (cvo + acc0[qq]) + b2v;
                    unsigned short ch, cl;
                    split2(cv, ch, cl);
                    sChi[r][dcol] = ch;
                    sClo[r][dcol] = cl;
                }
                #pragma unroll
                for (int qq = 0; qq < 4; ++qq) {
                    const int r = 16 + q * 4 + qq;
                    const float cvo = bf2f(sChi[r][dcol]) + bf2f(sClo[r][dcol]);
                    const float cv = (cvo + acc1[qq]) + b2v;
                    unsigned short ch, cl;
                    split2(cv, ch, cl);
                    sChi[r][dcol] = ch;
                    sClo[r][dcol] = cl;
                }
            }
        }
        __syncthreads();
    }

    // ---- fast dists ----
    if (t < 128) {
        const int row = t >> 2, seg = t & 3;
        float qa = 0.f;
        #pragma unroll
        for (int dd = 0; dd < 32; ++dd) {
            const int d = seg * 32 + dd;
            const float cv = bf2f(sChi[row][d]) + bf2f(sClo[row][d]);
            const float e = sr[d] - cv;
            qa = fmaf(e, e, qa);
        }
        qa += __shfl_xor(qa, 1);
        qa += __shfl_xor(qa, 2);
        if (seg == 0) gdist[(size_t)n * K_ + k0 + row] = qa;
    }
}

// ---------------------------------------------------------------------------
// refine kernel: per n — argmin + exact f64 refinement + outputs + state.
// ---------------------------------------------------------------------------
__launch_bounds__(256, 2)
__global__ void refine_kernel(const int m,
                              const float* __restrict__ z,
                              const float* __restrict__ cp_w,
                              const float* __restrict__ cp_b,
                              const float* __restrict__ w1,
                              const float* __restrict__ b1,
                              const float* __restrict__ w2,
                              const float* __restrict__ b2,
                              const float* __restrict__ Bb,
                              const float* __restrict__ gdist,
                              float* __restrict__ xhat,
                              float* __restrict__ Ag,
                              float* __restrict__ out0,
                              float* __restrict__ out1,
                              float* __restrict__ out2,
                              float* __restrict__ out3) {
    __shared__ float sxhat[D_], sA[D_], sr[D_], scb[D_], scsel[D_], sE[D_];
    __shared__ float shrow[H_];
    __shared__ float sdist[K_];
    __shared__ int   sflag[K_];
    __shared__ double sdd[2];
    __shared__ float smin, sbest;
    __shared__ int   sbidx, supd;

    const int n = blockIdx.x;
    const int t = threadIdx.x;

    if (t < D_) {
        const float xh = xhat[(size_t)n * D_ + t];
        sxhat[t] = xh;
        sA[t]    = Ag[(size_t)n * D_ + t];
        scb[t]   = cp_b[m * D_ + t];
        const float zv = z[(size_t)n * D_ + t];
        const float rv = zv - xh;
        sr[t] = rv;
        out2[((size_t)m * N_ + n) * D_ + t] = rv;
    }
    sdist[t] = gdist[(size_t)n * K_ + t];
    __syncthreads();

    if (t < 64) {
        float bv = 1e30f; int bx = 0;
        #pragma unroll
        for (int u = 0; u < 4; ++u) {
            const int idx = t * 4 + u;
            const float v = sdist[idx];
            if (v < bv) { bv = v; bx = idx; }
        }
        #pragma unroll
        for (int s = 1; s < 64; s <<= 1) {
            const float ov = __shfl_xor(bv, s);
            const int   ox = __shfl_xor(bx, s);
            if (ov < bv || (ov == bv && ox < bx)) { bv = ov; bx = ox; }
        }
        if (t == 0) smin = bv;
    }
    __syncthreads();
    sflag[t] = (sdist[t] <= smin + EPS_) ? 1 : 0;
    if (t == 0) { sbest = 1e30f; sbidx = 0; }
    __syncthreads();

    for (int k = 0; k < K_; ++k) {
        if (!sflag[k]) continue;
        if (t < D_)
            sE[t] = (sA[t] + Bb[((size_t)(m * K_ + k)) * D_ + t]) + scb[t];
        __syncthreads();
        for (int i = 0; i < NB_; ++i) {
            const int bi = m * NB_ + i;
            {
                const f32x4* wp = (const f32x4*)(w1 + ((size_t)bi * H_ + t) * D_);
                double h0 = 0, h1 = 0, h2 = 0, h3 = 0;
                #pragma unroll 8
                for (int u = 0; u < 32; ++u) {
                    f32x4 wv = wp[u];
                    h0 += (double)(sE[u * 4 + 0] * wv[0]);
                    h1 += (double)(sE[u * 4 + 1] * wv[1]);
                    h2 += (double)(sE[u * 4 + 2] * wv[2]);
                    h3 += (double)(sE[u * 4 + 3] * wv[3]);
                }
                const float hv = (float)((h0 + h1) + (h2 + h3)) + b1[(size_t)bi * H_ + t];
                shrow[t] = fmaxf(hv, 0.0f);
            }
            __syncthreads();
            if (t < D_) {
                const f32x4* wp = (const f32x4*)(w2 + ((size_t)bi * D_ + t) * H_);
                double s0 = 0, s1 = 0, s2 = 0, s3 = 0;
                #pragma unroll 8
                for (int u = 0; u < 64; ++u) {
                    f32x4 wv = wp[u];
                    s0 += (double)(shrow[u * 4 + 0] * wv[0]);
                    s1 += (double)(shrow[u * 4 + 1] * wv[1]);
                    s2 += (double)(shrow[u * 4 + 2] * wv[2]);
                    s3 += (double)(shrow[u * 4 + 3] * wv[3]);
                }
                sE[t] = (sE[t] + (float)((s0 + s1) + (s2 + s3))) + b2[(size_t)bi * D_ + t];
            }
            __syncthreads();
        }
        {
            double dp = 0.0;
            if (t < D_) {
                const float e = sr[t] - sE[t];
                const float e2 = e * e;
                dp = (double)e2;
                #pragma unroll
                for (int s = 1; s < 64; s <<= 1) dp += __shfl_xor(dp, s);
                if ((t & 63) == 0) sdd[t >> 6] = dp;
            }
        }
        __syncthreads();
        if (t == 0) {
            const float df = (float)(sdd[0] + sdd[1]);
            if (df < sbest) { sbest = df; sbidx = k; supd = 1; }
            else supd = 0;
        }
        __syncthreads();
        if (supd && t < D_) scsel[t] = sE[t];
        __syncthreads();
    }

    if (t == 0) out1[(size_t)n * M_ + m] = (float)sbidx;

    if (t < D_) {
        const float cs = scsel[t];
        out3[((size_t)m * N_ + n) * D_ + t] = cs;
        const float xnew = sxhat[t] + cs;
        xhat[(size_t)n * D_ + t] = xnew;
        sxhat[t] = xnew;
        if (m == M_ - 1) {
            const float zv = z[(size_t)n * D_ + t];
            out0[(size_t)n * D_ + t] = zv + (xnew - zv);
        }
    }
    __syncthreads();

    if (m < M_ - 1 && t < D_) {
        const f32x4* wp = (const f32x4*)(cp_w + ((size_t)((m + 1) * D_ + t)) * (2 * D_));
        double a0 = 0, a1 = 0, a2 = 0, a3 = 0;
        #pragma unroll 8
        for (int u = 0; u < 32; ++u) {
            f32x4 wv = wp[u];
            a0 += (double)(sxhat[u * 4 + 0] * wv[0]);
            a1 += (double)(sxhat[u * 4 + 1] * wv[1]);
            a2 += (double)(sxhat[u * 4 + 2] * wv[2]);
            a3 += (double)(sxhat[u * 4 + 3] * wv[3]);
        }
        Ag[(size_t)n * D_ + t] = (float)((a0 + a1) + (a2 + a3));
    }
}

extern "C" void kernel_launch(void* const* d_in, const int* in_sizes, int n_in,
                              void* d_out, int out_size, void* d_ws, size_t ws_size,
                              hipStream_t stream) {
    const float* z       = (const float*)d_in[0];
    const float* base_cb = (const float*)d_in[1];
    const float* cp_w    = (const float*)d_in[2];
    const float* cp_b    = (const float*)d_in[3];
    const float* w1      = (const float*)d_in[4];
    const float* b1      = (const float*)d_in[5];
    const float* w2      = (const float*)d_in[6];
    const float* b2      = (const float*)d_in[7];

    float* out  = (float*)d_out;
    float* out0 = out;
    float* out1 = out0 + (size_t)N_ * D_;
    float* out2 = out1 + (size_t)N_ * M_;
    float* out3 = out2 + (size_t)M_ * N_ * D_;

    // ws: Bb 512K | w1hi 512K | w1lo 512K | w2hi 512K | w2lo 512K
    //     | xhat 512K | A 512K | gdist 1M   (total 4.5 MB)
    char* ws = (char*)d_ws;
    float*          Bb    = (float*)(ws + 0);
    unsigned short* w1hi  = (unsigned short*)(ws + 524288);
    unsigned short* w1lo  = (unsigned short*)(ws + 1048576);
    unsigned short* w2hi  = (unsigned short*)(ws + 1572864);
    unsigned short* w2lo  = (unsigned short*)(ws + 2097152);
    float*          xhat  = (float*)(ws + 2621440);
    float*          Ag    = (float*)(ws + 3145728);
    float*          gdist = (float*)(ws + 3670016);

    hipLaunchKernelGGL(precompute_Bb, dim3(M_ * K_), dim3(D_), 0, stream,
                       base_cb, cp_w, Bb);
    hipLaunchKernelGGL(convert_w, dim3(1024), dim3(256), 0, stream,
                       w1, w2, w1hi, w1lo, w2hi, w2lo);
    hipLaunchKernelGGL(init_state, dim3(512), dim3(256), 0, stream, xhat, Ag);

    for (int m = 0; m < M_; ++m) {
        hipLaunchKernelGGL(dist_kernel, dim3(N_ * 8), dim3(256), 0, stream,
                           m, z, cp_b, xhat, Ag, Bb,
                           w1hi, w1lo, w2hi, w2lo, b1, b2, gdist);
        hipLaunchKernelGGL(refine_kernel, dim3(N_), dim3(256), 0, stream,
                           m, z, cp_w, cp_b, w1, b1, w2, b2, Bb, gdist,
                           xhat, Ag, out0, out1, out2, out3);
    }
}

// Round 6
// 2420.844 us; speedup vs baseline: 1.1557x; 1.1557x over previous
//
#include <hip/hip_runtime.h>

#define N_ 1024
#define D_ 128
#define K_ 256
#define M_ 4
#define H_ 256
#define NB_ 2
#define KT_ 32
#define EPS_ 0.10f
#define CHPAD 136   // shorts per row; 272 B (16B-aligned rows)

typedef _Float16 half8 __attribute__((ext_vector_type(8)));
typedef __attribute__((ext_vector_type(8))) short short8;
typedef __attribute__((ext_vector_type(4))) float f32x4;

__device__ inline unsigned short h2s(_Float16 h) {
    return __builtin_bit_cast(unsigned short, h);
}
__device__ inline float s2f(unsigned short s) {
    return (float)__builtin_bit_cast(_Float16, s);
}
__device__ inline void split2h(float x, unsigned short& hi, unsigned short& lo) {
    _Float16 h = (_Float16)x;                 // RNE, 11-bit mantissa
    _Float16 l = (_Float16)(x - (float)h);    // next ~11 bits
    hi = __builtin_bit_cast(unsigned short, h);
    lo = __builtin_bit_cast(unsigned short, l);
}

// ---------------------------------------------------------------------------
// Bb[m,k,d] = f32( exact_sum_d' cb[k,d'] * cp_w[m,d,D+d'] )
// ---------------------------------------------------------------------------
__global__ void precompute_Bb(const float* __restrict__ base_cb,
                              const float* __restrict__ cp_w,
                              float* __restrict__ Bb) {
    const int mk = blockIdx.x;
    const int m  = mk >> 8;
    const int d  = threadIdx.x;
    const float* cb = base_cb + (size_t)mk * D_;
    const float* wc = cp_w + ((size_t)(m * D_ + d)) * (2 * D_) + D_;
    double a0 = 0, a1 = 0, a2 = 0, a3 = 0;
    #pragma unroll
    for (int dp = 0; dp < D_; dp += 4) {
        a0 += (double)(cb[dp + 0] * wc[dp + 0]);
        a1 += (double)(cb[dp + 1] * wc[dp + 1]);
        a2 += (double)(cb[dp + 2] * wc[dp + 2]);
        a3 += (double)(cb[dp + 3] * wc[dp + 3]);
    }
    Bb[(size_t)mk * D_ + d] = (float)((a0 + a1) + (a2 + a3));
}

__global__ void convert_w(const float* __restrict__ w1,
                          const float* __restrict__ w2,
                          unsigned short* __restrict__ w1h,
                          unsigned short* __restrict__ w1l,
                          unsigned short* __restrict__ w2h,
                          unsigned short* __restrict__ w2l) {
    const int i = blockIdx.x * blockDim.x + threadIdx.x;
    unsigned short h, l;
    split2h(w1[i], h, l); w1h[i] = h; w1l[i] = l;
    split2h(w2[i], h, l); w2h[i] = h; w2l[i] = l;
}

__global__ void init_state(float* __restrict__ xhat, float* __restrict__ Ag) {
    const int i = blockIdx.x * blockDim.x + threadIdx.x;
    xhat[i] = 0.0f;
    Ag[i] = 0.0f;
}

// ---------------------------------------------------------------------------
// dist kernel: block (n, kt) -> fast dists for 32 codewords via f16-split
// 3-pass MFMA. H processed in two 128-col halves (LDS 36 KB -> 4 blocks/CU).
// ---------------------------------------------------------------------------
__launch_bounds__(256, 4)
__global__ void dist_kernel(const int m,
                            const float* __restrict__ z,
                            const float* __restrict__ cp_b,
                            const float* __restrict__ xhat,
                            const float* __restrict__ Ag,
                            const float* __restrict__ Bb,
                            const unsigned short* __restrict__ w1hi,
                            const unsigned short* __restrict__ w1lo,
                            const unsigned short* __restrict__ w2hi,
                            const unsigned short* __restrict__ w2lo,
                            const float* __restrict__ b1,
                            const float* __restrict__ b2,
                            float* __restrict__ gdist) {
    __shared__ alignas(16) unsigned short sChi[KT_][CHPAD];
    __shared__ alignas(16) unsigned short sClo[KT_][CHPAD];
    __shared__ alignas(16) unsigned short sHhi[KT_][CHPAD];  // 128 j's per half
    __shared__ alignas(16) unsigned short sHlo[KT_][CHPAD];
    __shared__ float sA[D_], sr[D_], scb[D_];

    const int bid  = blockIdx.x;
    const int n    = bid >> 3;
    const int k0   = (bid & 7) * KT_;
    const int t    = threadIdx.x;
    const int wid  = t >> 6;
    const int lane = t & 63;
    const int l15  = lane & 15;
    const int q    = lane >> 4;

    if (t < D_) {
        sA[t]  = Ag[(size_t)n * D_ + t];
        sr[t]  = z[(size_t)n * D_ + t] - xhat[(size_t)n * D_ + t];
        scb[t] = cp_b[m * D_ + t];
    }
    __syncthreads();

    // ---- C init: C = (A + Bb) + cp_b, f16 hi/lo split, b128 stores ----
    {
        const int row  = t >> 3;
        const int dblk = (t & 7) * 16;
        const f32x4* bb4 = (const f32x4*)(Bb + ((size_t)(m * K_ + k0 + row)) * D_ + dblk);
        #pragma unroll
        for (int g = 0; g < 2; ++g) {
            const f32x4 v0 = bb4[g * 2];
            const f32x4 v1 = bb4[g * 2 + 1];
            short8 hs, ls;
            #pragma unroll
            for (int x = 0; x < 8; ++x) {
                const int d = dblk + g * 8 + x;
                const float bv = (x < 4) ? v0[x] : v1[x - 4];
                const float cv = (sA[d] + bv) + scb[d];
                unsigned short ch, cl;
                split2h(cv, ch, cl);
                hs[x] = (short)ch;
                ls[x] = (short)cl;
            }
            *(short8*)&sChi[row][dblk + g * 8] = hs;
            *(short8*)&sClo[row][dblk + g * 8] = ls;
        }
    }
    __syncthreads();

    for (int i = 0; i < NB_; ++i) {
        const int bi = m * NB_ + i;
        const unsigned short* w1h = w1hi + (size_t)bi * H_ * D_;
        const unsigned short* w1l = w1lo + (size_t)bi * H_ * D_;
        const unsigned short* w2h = w2hi + (size_t)bi * D_ * H_;
        const unsigned short* w2l = w2lo + (size_t)bi * D_ * H_;

        f32x4 acc0[2], acc1[2];
        #pragma unroll
        for (int u = 0; u < 2; ++u) {
            acc0[u] = (f32x4){0.f, 0.f, 0.f, 0.f};
            acc1[u] = (f32x4){0.f, 0.f, 0.f, 0.f};
        }

        #pragma unroll
        for (int half = 0; half < 2; ++half) {
            // ---- GEMM1 (128 j's): h = relu(C @ W1^T + b1) ----
            #pragma unroll
            for (int u = 0; u < 2; ++u) {
                const int jcol = wid * 32 + u * 16 + l15;   // 0..127
                const int jg   = half * 128 + jcol;
                const size_t wbase = (size_t)jg * D_ + q * 8;
                half8 bh[4], bl[4];
                #pragma unroll
                for (int kk = 0; kk < 4; ++kk) {
                    bh[kk] = *(const half8*)(w1h + wbase + kk * 32);
                    bl[kk] = *(const half8*)(w1l + wbase + kk * 32);
                }
                const float b1v = b1[(size_t)bi * H_ + jg];
                #pragma unroll
                for (int mt = 0; mt < 2; ++mt) {
                    const int r = mt * 16 + l15;
                    f32x4 acc = {0.f, 0.f, 0.f, 0.f};
                    #pragma unroll
                    for (int kk = 0; kk < 4; ++kk) {
                        half8 ah = *(const half8*)&sChi[r][kk * 32 + q * 8];
                        half8 al = *(const half8*)&sClo[r][kk * 32 + q * 8];
                        acc = __builtin_amdgcn_mfma_f32_16x16x32_f16(ah, bh[kk], acc, 0, 0, 0);
                        acc = __builtin_amdgcn_mfma_f32_16x16x32_f16(ah, bl[kk], acc, 0, 0, 0);
                        acc = __builtin_amdgcn_mfma_f32_16x16x32_f16(al, bh[kk], acc, 0, 0, 0);
                    }
                    #pragma unroll
                    for (int qq = 0; qq < 4; ++qq) {
                        const float hv = fmaxf(acc[qq] + b1v, 0.0f);
                        unsigned short hh, hl;
                        split2h(hv, hh, hl);
                        sHhi[mt * 16 + q * 4 + qq][jcol] = hh;
                        sHlo[mt * 16 + q * 4 + qq][jcol] = hl;
                    }
                }
            }
            __syncthreads();

            // ---- GEMM2 partial: acc += h_half @ W2_half^T ----
            #pragma unroll
            for (int u = 0; u < 2; ++u) {
                const int dcol = (wid * 2 + u) * 16 + l15;  // 0..127
                const size_t wbase = (size_t)dcol * H_ + half * 128 + q * 8;
                #pragma unroll
                for (int kk = 0; kk < 4; ++kk) {
                    half8 bh = *(const half8*)(w2h + wbase + kk * 32);
                    half8 bl = *(const half8*)(w2l + wbase + kk * 32);
                    half8 ah0 = *(const half8*)&sHhi[l15][kk * 32 + q * 8];
                    half8 al0 = *(const half8*)&sHlo[l15][kk * 32 + q * 8];
                    acc0[u] = __builtin_amdgcn_mfma_f32_16x16x32_f16(ah0, bh, acc0[u], 0, 0, 0);
                    acc0[u] = __builtin_amdgcn_mfma_f32_16x16x32_f16(ah0, bl, acc0[u], 0, 0, 0);
                    acc0[u] = __builtin_amdgcn_mfma_f32_16x16x32_f16(al0, bh, acc0[u], 0, 0, 0);
                    half8 ah1 = *(const half8*)&sHhi[16 + l15][kk * 32 + q * 8];
                    half8 al1 = *(const half8*)&sHlo[16 + l15][kk * 32 + q * 8];
                    acc1[u] = __builtin_amdgcn_mfma_f32_16x16x32_f16(ah1, bh, acc1[u], 0, 0, 0);
                    acc1[u] = __builtin_amdgcn_mfma_f32_16x16x32_f16(ah1, bl, acc1[u], 0, 0, 0);
                    acc1[u] = __builtin_amdgcn_mfma_f32_16x16x32_f16(al1, bh, acc1[u], 0, 0, 0);
                }
            }
            if (half == 0) __syncthreads();   // sH reused by next half's GEMM1
        }

        // ---- C update (no barrier needed: only sC touched, no readers) ----
        #pragma unroll
        for (int u = 0; u < 2; ++u) {
            const int dcol = (wid * 2 + u) * 16 + l15;
            const float b2v = b2[(size_t)bi * D_ + dcol];
            #pragma unroll
            for (int qq = 0; qq < 4; ++qq) {
                const int r = q * 4 + qq;
                const float cvo = s2f(sChi[r][dcol]) + s2f(sClo[r][dcol]);
                const float cv = (cvo + acc0[u][qq]) + b2v;
                unsigned short ch, cl;
                split2h(cv, ch, cl);
                sChi[r][dcol] = ch;
                sClo[r][dcol] = cl;
            }
            #pragma unroll
            for (int qq = 0; qq < 4; ++qq) {
                const int r = 16 + q * 4 + qq;
                const float cvo = s2f(sChi[r][dcol]) + s2f(sClo[r][dcol]);
                const float cv = (cvo + acc1[u][qq]) + b2v;
                unsigned short ch, cl;
                split2h(cv, ch, cl);
                sChi[r][dcol] = ch;
                sClo[r][dcol] = cl;
            }
        }
        __syncthreads();
    }

    // ---- fast dists ----
    if (t < 128) {
        const int row = t >> 2, seg = t & 3;
        float qa = 0.f;
        #pragma unroll
        for (int dd = 0; dd < 32; ++dd) {
            const int d = seg * 32 + dd;
            const float cv = s2f(sChi[row][d]) + s2f(sClo[row][d]);
            const float e = sr[d] - cv;
            qa = fmaf(e, e, qa);
        }
        qa += __shfl_xor(qa, 1);
        qa += __shfl_xor(qa, 2);
        if (seg == 0) gdist[(size_t)n * K_ + k0 + row] = qa;
    }
}

// ---------------------------------------------------------------------------
// refine kernel: per n — argmin + exact f64 refinement + outputs + state.
// ---------------------------------------------------------------------------
__launch_bounds__(256, 2)
__global__ void refine_kernel(const int m,
                              const float* __restrict__ z,
                              const float* __restrict__ cp_w,
                              const float* __restrict__ cp_b,
                              const float* __restrict__ w1,
                              const float* __restrict__ b1,
                              const float* __restrict__ w2,
                              const float* __restrict__ b2,
                              const float* __restrict__ Bb,
                              const float* __restrict__ gdist,
                              float* __restrict__ xhat,
                              float* __restrict__ Ag,
                              float* __restrict__ out0,
                              float* __restrict__ out1,
                              float* __restrict__ out2,
                              float* __restrict__ out3) {
    __shared__ float sxhat[D_], sA[D_], sr[D_], scb[D_], scsel[D_], sE[D_];
    __shared__ float shrow[H_];
    __shared__ float sdist[K_];
    __shared__ int   sflag[K_];
    __shared__ double sdd[2];
    __shared__ float smin, sbest;
    __shared__ int   sbidx, supd;

    const int n = blockIdx.x;
    const int t = threadIdx.x;

    if (t < D_) {
        const float xh = xhat[(size_t)n * D_ + t];
        sxhat[t] = xh;
        sA[t]    = Ag[(size_t)n * D_ + t];
        scb[t]   = cp_b[m * D_ + t];
        const float zv = z[(size_t)n * D_ + t];
        const float rv = zv - xh;
        sr[t] = rv;
        out2[((size_t)m * N_ + n) * D_ + t] = rv;
    }
    sdist[t] = gdist[(size_t)n * K_ + t];
    __syncthreads();

    if (t < 64) {
        float bv = 1e30f; int bx = 0;
        #pragma unroll
        for (int u = 0; u < 4; ++u) {
            const int idx = t * 4 + u;
            const float v = sdist[idx];
            if (v < bv) { bv = v; bx = idx; }
        }
        #pragma unroll
        for (int s = 1; s < 64; s <<= 1) {
            const float ov = __shfl_xor(bv, s);
            const int   ox = __shfl_xor(bx, s);
            if (ov < bv || (ov == bv && ox < bx)) { bv = ov; bx = ox; }
        }
        if (t == 0) smin = bv;
    }
    __syncthreads();
    sflag[t] = (sdist[t] <= smin + EPS_) ? 1 : 0;
    if (t == 0) { sbest = 1e30f; sbidx = 0; }
    __syncthreads();

    for (int k = 0; k < K_; ++k) {
        if (!sflag[k]) continue;
        if (t < D_)
            sE[t] = (sA[t] + Bb[((size_t)(m * K_ + k)) * D_ + t]) + scb[t];
        __syncthreads();
        for (int i = 0; i < NB_; ++i) {
            const int bi = m * NB_ + i;
            {
                const f32x4* wp = (const f32x4*)(w1 + ((size_t)bi * H_ + t) * D_);
                double h0 = 0, h1 = 0, h2 = 0, h3 = 0;
                #pragma unroll 8
                for (int u = 0; u < 32; ++u) {
                    f32x4 wv = wp[u];
                    h0 += (double)(sE[u * 4 + 0] * wv[0]);
                    h1 += (double)(sE[u * 4 + 1] * wv[1]);
                    h2 += (double)(sE[u * 4 + 2] * wv[2]);
                    h3 += (double)(sE[u * 4 + 3] * wv[3]);
                }
                const float hv = (float)((h0 + h1) + (h2 + h3)) + b1[(size_t)bi * H_ + t];
                shrow[t] = fmaxf(hv, 0.0f);
            }
            __syncthreads();
            if (t < D_) {
                const f32x4* wp = (const f32x4*)(w2 + ((size_t)bi * D_ + t) * H_);
                double s0 = 0, s1 = 0, s2 = 0, s3 = 0;
                #pragma unroll 8
                for (int u = 0; u < 64; ++u) {
                    f32x4 wv = wp[u];
                    s0 += (double)(shrow[u * 4 + 0] * wv[0]);
                    s1 += (double)(shrow[u * 4 + 1] * wv[1]);
                    s2 += (double)(shrow[u * 4 + 2] * wv[2]);
                    s3 += (double)(shrow[u * 4 + 3] * wv[3]);
                }
                sE[t] = (sE[t] + (float)((s0 + s1) + (s2 + s3))) + b2[(size_t)bi * D_ + t];
            }
            __syncthreads();
        }
        {
            double dp = 0.0;
            if (t < D_) {
                const float e = sr[t] - sE[t];
                const float e2 = e * e;
                dp = (double)e2;
                #pragma unroll
                for (int s = 1; s < 64; s <<= 1) dp += __shfl_xor(dp, s);
                if ((t & 63) == 0) sdd[t >> 6] = dp;
            }
        }
        __syncthreads();
        if (t == 0) {
            const float df = (float)(sdd[0] + sdd[1]);
            if (df < sbest) { sbest = df; sbidx = k; supd = 1; }
            else supd = 0;
        }
        __syncthreads();
        if (supd && t < D_) scsel[t] = sE[t];
        __syncthreads();
    }

    if (t == 0) out1[(size_t)n * M_ + m] = (float)sbidx;

    if (t < D_) {
        const float cs = scsel[t];
        out3[((size_t)m * N_ + n) * D_ + t] = cs;
        const float xnew = sxhat[t] + cs;
        xhat[(size_t)n * D_ + t] = xnew;
        sxhat[t] = xnew;
        if (m == M_ - 1) {
            const float zv = z[(size_t)n * D_ + t];
            out0[(size_t)n * D_ + t] = zv + (xnew - zv);
        }
    }
    __syncthreads();

    if (m < M_ - 1 && t < D_) {
        const f32x4* wp = (const f32x4*)(cp_w + ((size_t)((m + 1) * D_ + t)) * (2 * D_));
        double a0 = 0, a1 = 0, a2 = 0, a3 = 0;
        #pragma unroll 8
        for (int u = 0; u < 32; ++u) {
            f32x4 wv = wp[u];
            a0 += (double)(sxhat[u * 4 + 0] * wv[0]);
            a1 += (double)(sxhat[u * 4 + 1] * wv[1]);
            a2 += (double)(sxhat[u * 4 + 2] * wv[2]);
            a3 += (double)(sxhat[u * 4 + 3] * wv[3]);
        }
        Ag[(size_t)n * D_ + t] = (float)((a0 + a1) + (a2 + a3));
    }
}

extern "C" void kernel_launch(void* const* d_in, const int* in_sizes, int n_in,
                              void* d_out, int out_size, void* d_ws, size_t ws_size,
                              hipStream_t stream) {
    const float* z       = (const float*)d_in[0];
    const float* base_cb = (const float*)d_in[1];
    const float* cp_w    = (const float*)d_in[2];
    const float* cp_b    = (const float*)d_in[3];
    const float* w1      = (const float*)d_in[4];
    const float* b1      = (const float*)d_in[5];
    const float* w2      = (const float*)d_in[6];
    const float* b2      = (const float*)d_in[7];

    float* out  = (float*)d_out;
    float* out0 = out;
    float* out1 = out0 + (size_t)N_ * D_;
    float* out2 = out1 + (size_t)N_ * M_;
    float* out3 = out2 + (size_t)M_ * N_ * D_;

    char* ws = (char*)d_ws;
    float*          Bb    = (float*)(ws + 0);
    unsigned short* w1hi  = (unsigned short*)(ws + 524288);
    unsigned short* w1lo  = (unsigned short*)(ws + 1048576);
    unsigned short* w2hi  = (unsigned short*)(ws + 1572864);
    unsigned short* w2lo  = (unsigned short*)(ws + 2097152);
    float*          xhat  = (float*)(ws + 2621440);
    float*          Ag    = (float*)(ws + 3145728);
    float*          gdist = (float*)(ws + 3670016);

    hipLaunchKernelGGL(precompute_Bb, dim3(M_ * K_), dim3(D_), 0, stream,
                       base_cb, cp_w, Bb);
    hipLaunchKernelGGL(convert_w, dim3(1024), dim3(256), 0, stream,
                       w1, w2, w1hi, w1lo, w2hi, w2lo);
    hipLaunchKernelGGL(init_state, dim3(512), dim3(256), 0, stream, xhat, Ag);

    for (int m = 0; m < M_; ++m) {
        hipLaunchKernelGGL(dist_kernel, dim3(N_ * 8), dim3(256), 0, stream,
                           m, z, cp_b, xhat, Ag, Bb,
                           w1hi, w1lo, w2hi, w2lo, b1, b2, gdist);
        hipLaunchKernelGGL(refine_kernel, dim3(N_), dim3(256), 0, stream,
                           m, z, cp_w, cp_b, w1, b1, w2, b2, Bb, gdist,
                           xhat, Ag, out0, out1, out2, out3);
    }
}

// Round 7
// 2323.010 us; speedup vs baseline: 1.2044x; 1.0421x over previous
//
#include <hip/hip_runtime.h>

#define N_ 1024
#define D_ 128
#define K_ 256
#define M_ 4
#define H_ 256
#define NB_ 2
#define KT_ 32
#define EPS_ 0.02f
#define CHPAD 136   // shorts per C row  (272 B, 16B-aligned, stride 4 banks)
#define HPAD  264   // shorts per H row  (528 B, 16B-aligned, stride 4 banks)

typedef _Float16 half8 __attribute__((ext_vector_type(8)));
typedef __attribute__((ext_vector_type(8))) short short8;
typedef __attribute__((ext_vector_type(4))) float f32x4;
typedef __attribute__((ext_vector_type(16))) float f32x16;

__device__ inline float s2f(unsigned short s) {
    return (float)__builtin_bit_cast(_Float16, s);
}
__device__ inline void split2h(float x, unsigned short& hi, unsigned short& lo) {
    _Float16 h = (_Float16)x;                 // RNE, 11-bit mantissa
    _Float16 l = (_Float16)(x - (float)h);    // next ~11 bits
    hi = __builtin_bit_cast(unsigned short, h);
    lo = __builtin_bit_cast(unsigned short, l);
}
__device__ inline f32x16 zero16() {
    f32x16 v;
    #pragma unroll
    for (int i = 0; i < 16; ++i) v[i] = 0.0f;
    return v;
}

// ---------------------------------------------------------------------------
// Bb[m,k,d] = f32( exact_sum_d' cb[k,d'] * cp_w[m,d,D+d'] )
// ---------------------------------------------------------------------------
__global__ void precompute_Bb(const float* __restrict__ base_cb,
                              const float* __restrict__ cp_w,
                              float* __restrict__ Bb) {
    const int mk = blockIdx.x;
    const int m  = mk >> 8;
    const int d  = threadIdx.x;
    const float* cb = base_cb + (size_t)mk * D_;
    const float* wc = cp_w + ((size_t)(m * D_ + d)) * (2 * D_) + D_;
    double a0 = 0, a1 = 0, a2 = 0, a3 = 0;
    #pragma unroll
    for (int dp = 0; dp < D_; dp += 4) {
        a0 += (double)(cb[dp + 0] * wc[dp + 0]);
        a1 += (double)(cb[dp + 1] * wc[dp + 1]);
        a2 += (double)(cb[dp + 2] * wc[dp + 2]);
        a3 += (double)(cb[dp + 3] * wc[dp + 3]);
    }
    Bb[(size_t)mk * D_ + d] = (float)((a0 + a1) + (a2 + a3));
}

__global__ void convert_w(const float* __restrict__ w1,
                          const float* __restrict__ w2,
                          unsigned short* __restrict__ w1h,
                          unsigned short* __restrict__ w1l,
                          unsigned short* __restrict__ w2h,
                          unsigned short* __restrict__ w2l) {
    const int i = blockIdx.x * blockDim.x + threadIdx.x;
    unsigned short h, l;
    split2h(w1[i], h, l); w1h[i] = h; w1l[i] = l;
    split2h(w2[i], h, l); w2h[i] = h; w2l[i] = l;
}

__global__ void init_state(float* __restrict__ xhat, float* __restrict__ Ag) {
    const int i = blockIdx.x * blockDim.x + threadIdx.x;
    xhat[i] = 0.0f;
    Ag[i] = 0.0f;
}

// ---------------------------------------------------------------------------
// dist kernel: block (n, kt) -> fast dists for 32 codewords via f16-split
// 3-pass 32x32x16 MFMA. Full-H in LDS; 2 barriers per NB block.
// ---------------------------------------------------------------------------
__launch_bounds__(256, 3)
__global__ void dist_kernel(const int m,
                            const float* __restrict__ z,
                            const float* __restrict__ cp_b,
                            const float* __restrict__ xhat,
                            const float* __restrict__ Ag,
                            const float* __restrict__ Bb,
                            const unsigned short* __restrict__ w1hi,
                            const unsigned short* __restrict__ w1lo,
                            const unsigned short* __restrict__ w2hi,
                            const unsigned short* __restrict__ w2lo,
                            const float* __restrict__ b1,
                            const float* __restrict__ b2,
                            float* __restrict__ gdist) {
    __shared__ alignas(16) unsigned short sChi[KT_][CHPAD];
    __shared__ alignas(16) unsigned short sClo[KT_][CHPAD];
    __shared__ alignas(16) unsigned short sHhi[KT_][HPAD];
    __shared__ alignas(16) unsigned short sHlo[KT_][HPAD];
    __shared__ float sA[D_], sr[D_], scb[D_];

    const int bid  = blockIdx.x;
    const int n    = bid >> 3;
    const int k0   = (bid & 7) * KT_;
    const int t    = threadIdx.x;
    const int wid  = t >> 6;
    const int lane = t & 63;
    const int l31  = lane & 31;
    const int koff = (lane >> 5) * 8;    // A/B k-offset for 32x32x16

    if (t < D_) {
        sA[t]  = Ag[(size_t)n * D_ + t];
        sr[t]  = z[(size_t)n * D_ + t] - xhat[(size_t)n * D_ + t];
        scb[t] = cp_b[m * D_ + t];
    }
    __syncthreads();

    // ---- C init: C = (A + Bb) + cp_b, f16 hi/lo split, b128 stores ----
    {
        const int row  = t >> 3;
        const int dblk = (t & 7) * 16;
        const f32x4* bb4 = (const f32x4*)(Bb + ((size_t)(m * K_ + k0 + row)) * D_ + dblk);
        #pragma unroll
        for (int g = 0; g < 2; ++g) {
            const f32x4 v0 = bb4[g * 2];
            const f32x4 v1 = bb4[g * 2 + 1];
            short8 hs, ls;
            #pragma unroll
            for (int x = 0; x < 8; ++x) {
                const int d = dblk + g * 8 + x;
                const float bv = (x < 4) ? v0[x] : v1[x - 4];
                const float cv = (sA[d] + bv) + scb[d];
                unsigned short ch, cl;
                split2h(cv, ch, cl);
                hs[x] = (short)ch;
                ls[x] = (short)cl;
            }
            *(short8*)&sChi[row][dblk + g * 8] = hs;
            *(short8*)&sClo[row][dblk + g * 8] = ls;
        }
    }
    __syncthreads();

    for (int i = 0; i < NB_; ++i) {
        const int bi = m * NB_ + i;
        const unsigned short* w1h = w1hi + (size_t)bi * H_ * D_;
        const unsigned short* w1l = w1lo + (size_t)bi * H_ * D_;
        const unsigned short* w2h = w2hi + (size_t)bi * D_ * H_;
        const unsigned short* w2l = w2lo + (size_t)bi * D_ * H_;

        // ---- GEMM1: h = relu(C @ W1^T + b1); wave handles j0 and j0+128 ----
        {
            const int j0 = wid * 32 + l31;
            const int j1 = j0 + 128;
            f32x16 accA = zero16();
            f32x16 accB = zero16();
            #pragma unroll
            for (int kt = 0; kt < 8; ++kt) {
                const int ko = kt * 16 + koff;
                half8 ah  = *(const half8*)&sChi[l31][ko];
                half8 al  = *(const half8*)&sClo[l31][ko];
                half8 bAh = *(const half8*)(w1h + (size_t)j0 * D_ + ko);
                half8 bAl = *(const half8*)(w1l + (size_t)j0 * D_ + ko);
                half8 bBh = *(const half8*)(w1h + (size_t)j1 * D_ + ko);
                half8 bBl = *(const half8*)(w1l + (size_t)j1 * D_ + ko);
                accA = __builtin_amdgcn_mfma_f32_32x32x16_f16(ah, bAh, accA, 0, 0, 0);
                accB = __builtin_amdgcn_mfma_f32_32x32x16_f16(ah, bBh, accB, 0, 0, 0);
                accA = __builtin_amdgcn_mfma_f32_32x32x16_f16(ah, bAl, accA, 0, 0, 0);
                accB = __builtin_amdgcn_mfma_f32_32x32x16_f16(ah, bBl, accB, 0, 0, 0);
                accA = __builtin_amdgcn_mfma_f32_32x32x16_f16(al, bAh, accA, 0, 0, 0);
                accB = __builtin_amdgcn_mfma_f32_32x32x16_f16(al, bBh, accB, 0, 0, 0);
            }
            const float b1A = b1[(size_t)bi * H_ + j0];
            const float b1B = b1[(size_t)bi * H_ + j1];
            #pragma unroll
            for (int reg = 0; reg < 16; ++reg) {
                const int krow = (reg & 3) + 8 * (reg >> 2) + 4 * (lane >> 5);
                unsigned short hh, hl;
                const float hA = fmaxf(accA[reg] + b1A, 0.0f);
                split2h(hA, hh, hl);
                sHhi[krow][j0] = hh;
                sHlo[krow][j0] = hl;
                const float hB = fmaxf(accB[reg] + b1B, 0.0f);
                split2h(hB, hh, hl);
                sHhi[krow][j1] = hh;
                sHlo[krow][j1] = hl;
            }
        }
        __syncthreads();

        // ---- GEMM2: C = (C + h @ W2^T) + b2; wave handles 32 d-cols ----
        {
            const int d = wid * 32 + l31;
            f32x16 acc0 = zero16();
            f32x16 acc1 = zero16();
            #pragma unroll
            for (int ht = 0; ht < 8; ++ht) {
                const int he = (2 * ht) * 16 + koff;
                const int ho = (2 * ht + 1) * 16 + koff;
                half8 aeh = *(const half8*)&sHhi[l31][he];
                half8 ael = *(const half8*)&sHlo[l31][he];
                half8 beh = *(const half8*)(w2h + (size_t)d * H_ + he);
                half8 bel = *(const half8*)(w2l + (size_t)d * H_ + he);
                half8 aoh = *(const half8*)&sHhi[l31][ho];
                half8 aol = *(const half8*)&sHlo[l31][ho];
                half8 boh = *(const half8*)(w2h + (size_t)d * H_ + ho);
                half8 bol = *(const half8*)(w2l + (size_t)d * H_ + ho);
                acc0 = __builtin_amdgcn_mfma_f32_32x32x16_f16(aeh, beh, acc0, 0, 0, 0);
                acc1 = __builtin_amdgcn_mfma_f32_32x32x16_f16(aoh, boh, acc1, 0, 0, 0);
                acc0 = __builtin_amdgcn_mfma_f32_32x32x16_f16(aeh, bel, acc0, 0, 0, 0);
                acc1 = __builtin_amdgcn_mfma_f32_32x32x16_f16(aoh, bol, acc1, 0, 0, 0);
                acc0 = __builtin_amdgcn_mfma_f32_32x32x16_f16(ael, beh, acc0, 0, 0, 0);
                acc1 = __builtin_amdgcn_mfma_f32_32x32x16_f16(aol, boh, acc1, 0, 0, 0);
            }
            const float b2v = b2[(size_t)bi * D_ + d];
            #pragma unroll
            for (int reg = 0; reg < 16; ++reg) {
                const int krow = (reg & 3) + 8 * (reg >> 2) + 4 * (lane >> 5);
                const float cvo = s2f(sChi[krow][d]) + s2f(sClo[krow][d]);
                const float cv  = (cvo + (acc0[reg] + acc1[reg])) + b2v;
                unsigned short ch, cl;
                split2h(cv, ch, cl);
                sChi[krow][d] = ch;
                sClo[krow][d] = cl;
            }
        }
        __syncthreads();
    }

    // ---- fast dists ----
    if (t < 128) {
        const int row = t >> 2, seg = t & 3;
        float qa = 0.f;
        #pragma unroll
        for (int dd = 0; dd < 32; ++dd) {
            const int d = seg * 32 + dd;
            const float cv = s2f(sChi[row][d]) + s2f(sClo[row][d]);
            const float e = sr[d] - cv;
            qa = fmaf(e, e, qa);
        }
        qa += __shfl_xor(qa, 1);
        qa += __shfl_xor(qa, 2);
        if (seg == 0) gdist[(size_t)n * K_ + k0 + row] = qa;
    }
}

// ---------------------------------------------------------------------------
// refine kernel: per n — argmin + exact f64 refinement + outputs + state.
// ---------------------------------------------------------------------------
__launch_bounds__(256, 4)
__global__ void refine_kernel(const int m,
                              const float* __restrict__ z,
                              const float* __restrict__ cp_w,
                              const float* __restrict__ cp_b,
                              const float* __restrict__ w1,
                              const float* __restrict__ b1,
                              const float* __restrict__ w2,
                              const float* __restrict__ b2,
                              const float* __restrict__ Bb,
                              const float* __restrict__ gdist,
                              float* __restrict__ xhat,
                              float* __restrict__ Ag,
                              float* __restrict__ out0,
                              float* __restrict__ out1,
                              float* __restrict__ out2,
                              float* __restrict__ out3) {
    __shared__ float sxhat[D_], sA[D_], sr[D_], scb[D_], scsel[D_], sE[D_];
    __shared__ float shrow[H_];
    __shared__ float sdist[K_];
    __shared__ int   sflag[K_];
    __shared__ double sdd[2];
    __shared__ float smin, sbest;
    __shared__ int   sbidx, supd;

    const int n = blockIdx.x;
    const int t = threadIdx.x;

    if (t < D_) {
        const float xh = xhat[(size_t)n * D_ + t];
        sxhat[t] = xh;
        sA[t]    = Ag[(size_t)n * D_ + t];
        scb[t]   = cp_b[m * D_ + t];
        const float zv = z[(size_t)n * D_ + t];
        const float rv = zv - xh;
        sr[t] = rv;
        out2[((size_t)m * N_ + n) * D_ + t] = rv;
    }
    sdist[t] = gdist[(size_t)n * K_ + t];
    __syncthreads();

    if (t < 64) {
        float bv = 1e30f; int bx = 0;
        #pragma unroll
        for (int u = 0; u < 4; ++u) {
            const int idx = t * 4 + u;
            const float v = sdist[idx];
            if (v < bv) { bv = v; bx = idx; }
        }
        #pragma unroll
        for (int s = 1; s < 64; s <<= 1) {
            const float ov = __shfl_xor(bv, s);
            const int   ox = __shfl_xor(bx, s);
            if (ov < bv || (ov == bv && ox < bx)) { bv = ov; bx = ox; }
        }
        if (t == 0) smin = bv;
    }
    __syncthreads();
    sflag[t] = (sdist[t] <= smin + EPS_) ? 1 : 0;
    if (t == 0) { sbest = 1e30f; sbidx = 0; }
    __syncthreads();

    for (int k = 0; k < K_; ++k) {
        if (!sflag[k]) continue;
        if (t < D_)
            sE[t] = (sA[t] + Bb[((size_t)(m * K_ + k)) * D_ + t]) + scb[t];
        __syncthreads();
        for (int i = 0; i < NB_; ++i) {
            const int bi = m * NB_ + i;
            {
                const f32x4* wp = (const f32x4*)(w1 + ((size_t)bi * H_ + t) * D_);
                double h0 = 0, h1 = 0, h2 = 0, h3 = 0;
                #pragma unroll 8
                for (int u = 0; u < 32; ++u) {
                    f32x4 wv = wp[u];
                    h0 += (double)(sE[u * 4 + 0] * wv[0]);
                    h1 += (double)(sE[u * 4 + 1] * wv[1]);
                    h2 += (double)(sE[u * 4 + 2] * wv[2]);
                    h3 += (double)(sE[u * 4 + 3] * wv[3]);
                }
                const float hv = (float)((h0 + h1) + (h2 + h3)) + b1[(size_t)bi * H_ + t];
                shrow[t] = fmaxf(hv, 0.0f);
            }
            __syncthreads();
            if (t < D_) {
                const f32x4* wp = (const f32x4*)(w2 + ((size_t)bi * D_ + t) * H_);
                double s0 = 0, s1 = 0, s2 = 0, s3 = 0;
                #pragma unroll 8
                for (int u = 0; u < 64; ++u) {
                    f32x4 wv = wp[u];
                    s0 += (double)(shrow[u * 4 + 0] * wv[0]);
                    s1 += (double)(shrow[u * 4 + 1] * wv[1]);
                    s2 += (double)(shrow[u * 4 + 2] * wv[2]);
                    s3 += (double)(shrow[u * 4 + 3] * wv[3]);
                }
                sE[t] = (sE[t] + (float)((s0 + s1) + (s2 + s3))) + b2[(size_t)bi * D_ + t];
            }
            __syncthreads();
        }
        {
            double dp = 0.0;
            if (t < D_) {
                const float e = sr[t] - sE[t];
                const float e2 = e * e;
                dp = (double)e2;
                #pragma unroll
                for (int s = 1; s < 64; s <<= 1) dp += __shfl_xor(dp, s);
                if ((t & 63) == 0) sdd[t >> 6] = dp;
            }
        }
        __syncthreads();
        if (t == 0) {
            const float df = (float)(sdd[0] + sdd[1]);
            if (df < sbest) { sbest = df; sbidx = k; supd = 1; }
            else supd = 0;
        }
        __syncthreads();
        if (supd && t < D_) scsel[t] = sE[t];
        __syncthreads();
    }

    if (t == 0) out1[(size_t)n * M_ + m] = (float)sbidx;

    if (t < D_) {
        const float cs = scsel[t];
        out3[((size_t)m * N_ + n) * D_ + t] = cs;
        const float xnew = sxhat[t] + cs;
        xhat[(size_t)n * D_ + t] = xnew;
        sxhat[t] = xnew;
        if (m == M_ - 1) {
            const float zv = z[(size_t)n * D_ + t];
            out0[(size_t)n * D_ + t] = zv + (xnew - zv);
        }
    }
    __syncthreads();

    if (m < M_ - 1 && t < D_) {
        const f32x4* wp = (const f32x4*)(cp_w + ((size_t)((m + 1) * D_ + t)) * (2 * D_));
        double a0 = 0, a1 = 0, a2 = 0, a3 = 0;
        #pragma unroll 8
        for (int u = 0; u < 32; ++u) {
            f32x4 wv = wp[u];
            a0 += (double)(sxhat[u * 4 + 0] * wv[0]);
            a1 += (double)(sxhat[u * 4 + 1] * wv[1]);
            a2 += (double)(sxhat[u * 4 + 2] * wv[2]);
            a3 += (double)(sxhat[u * 4 + 3] * wv[3]);
        }
        Ag[(size_t)n * D_ + t] = (float)((a0 + a1) + (a2 + a3));
    }
}

extern "C" void kernel_launch(void* const* d_in, const int* in_sizes, int n_in,
                              void* d_out, int out_size, void* d_ws, size_t ws_size,
                              hipStream_t stream) {
    const float* z       = (const float*)d_in[0];
    const float* base_cb = (const float*)d_in[1];
    const float* cp_w    = (const float*)d_in[2];
    const float* cp_b    = (const float*)d_in[3];
    const float* w1      = (const float*)d_in[4];
    const float* b1      = (const float*)d_in[5];
    const float* w2      = (const float*)d_in[6];
    const float* b2      = (const float*)d_in[7];

    float* out  = (float*)d_out;
    float* out0 = out;
    float* out1 = out0 + (size_t)N_ * D_;
    float* out2 = out1 + (size_t)N_ * M_;
    float* out3 = out2 + (size_t)M_ * N_ * D_;

    char* ws = (char*)d_ws;
    float*          Bb    = (float*)(ws + 0);
    unsigned short* w1hi  = (unsigned short*)(ws + 524288);
    unsigned short* w1lo  = (unsigned short*)(ws + 1048576);
    unsigned short* w2hi  = (unsigned short*)(ws + 1572864);
    unsigned short* w2lo  = (unsigned short*)(ws + 2097152);
    float*          xhat  = (float*)(ws + 2621440);
    float*          Ag    = (float*)(ws + 3145728);
    float*          gdist = (float*)(ws + 3670016);

    hipLaunchKernelGGL(precompute_Bb, dim3(M_ * K_), dim3(D_), 0, stream,
                       base_cb, cp_w, Bb);
    hipLaunchKernelGGL(convert_w, dim3(1024), dim3(256), 0, stream,
                       w1, w2, w1hi, w1lo, w2hi, w2lo);
    hipLaunchKernelGGL(init_state, dim3(512), dim3(256), 0, stream, xhat, Ag);

    for (int m = 0; m < M_; ++m) {
        hipLaunchKernelGGL(dist_kernel, dim3(N_ * 8), dim3(256), 0, stream,
                           m, z, cp_b, xhat, Ag, Bb,
                           w1hi, w1lo, w2hi, w2lo, b1, b2, gdist);
        hipLaunchKernelGGL(refine_kernel, dim3(N_), dim3(256), 0, stream,
                           m, z, cp_w, cp_b, w1, b1, w2, b2, Bb, gdist,
                           xhat, Ag, out0, out1, out2, out3);
    }
}

// Round 8
// 2303.937 us; speedup vs baseline: 1.2143x; 1.0083x over previous
//
#include <hip/hip_runtime.h>

#define N_ 1024
#define D_ 128
#define K_ 256
#define M_ 4
#define H_ 256
#define NB_ 2
#define KT_ 32
#define EPS_ 0.02f
#define CHPAD 136
#define HPAD  264

typedef _Float16 half8 __attribute__((ext_vector_type(8)));
typedef __attribute__((ext_vector_type(8))) short short8;
typedef __attribute__((ext_vector_type(4))) float f32x4;
typedef __attribute__((ext_vector_type(16))) float f32x16;

__device__ inline float s2f(unsigned short s) {
    return (float)__builtin_bit_cast(_Float16, s);
}
__device__ inline void split2h(float x, unsigned short& hi, unsigned short& lo) {
    _Float16 h = (_Float16)x;
    _Float16 l = (_Float16)(x - (float)h);
    hi = __builtin_bit_cast(unsigned short, h);
    lo = __builtin_bit_cast(unsigned short, l);
}
__device__ inline f32x16 zero16() {
    f32x16 v;
    #pragma unroll
    for (int i = 0; i < 16; ++i) v[i] = 0.0f;
    return v;
}

// ---------------------------------------------------------------------------
__global__ void precompute_Bb(const float* __restrict__ base_cb,
                              const float* __restrict__ cp_w,
                              float* __restrict__ Bb) {
    const int mk = blockIdx.x;
    const int m  = mk >> 8;
    const int d  = threadIdx.x;
    const float* cb = base_cb + (size_t)mk * D_;
    const float* wc = cp_w + ((size_t)(m * D_ + d)) * (2 * D_) + D_;
    double a0 = 0, a1 = 0, a2 = 0, a3 = 0;
    #pragma unroll
    for (int dp = 0; dp < D_; dp += 4) {
        a0 += (double)(cb[dp + 0] * wc[dp + 0]);
        a1 += (double)(cb[dp + 1] * wc[dp + 1]);
        a2 += (double)(cb[dp + 2] * wc[dp + 2]);
        a3 += (double)(cb[dp + 3] * wc[dp + 3]);
    }
    Bb[(size_t)mk * D_ + d] = (float)((a0 + a1) + (a2 + a3));
}

__global__ void convert_w(const float* __restrict__ w1,
                          const float* __restrict__ w2,
                          unsigned short* __restrict__ w1h,
                          unsigned short* __restrict__ w1l,
                          unsigned short* __restrict__ w2h,
                          unsigned short* __restrict__ w2l) {
    const int i = blockIdx.x * blockDim.x + threadIdx.x;
    unsigned short h, l;
    split2h(w1[i], h, l); w1h[i] = h; w1l[i] = l;
    split2h(w2[i], h, l); w2h[i] = h; w2l[i] = l;
}

__global__ void init_state(float* __restrict__ xhat, float* __restrict__ Ag) {
    const int i = blockIdx.x * blockDim.x + threadIdx.x;
    xhat[i] = 0.0f;
    Ag[i] = 0.0f;
}

// ---------------------------------------------------------------------------
// dist kernel: block (n, kt) -> fast dists for 32 codewords.
// Weight loads batched into register arrays (latency amortized), MFMA after.
// ---------------------------------------------------------------------------
__launch_bounds__(256, 3)
__global__ void dist_kernel(const int m,
                            const float* __restrict__ z,
                            const float* __restrict__ cp_b,
                            const float* __restrict__ xhat,
                            const float* __restrict__ Ag,
                            const float* __restrict__ Bb,
                            const unsigned short* __restrict__ w1hi,
                            const unsigned short* __restrict__ w1lo,
                            const unsigned short* __restrict__ w2hi,
                            const unsigned short* __restrict__ w2lo,
                            const float* __restrict__ b1,
                            const float* __restrict__ b2,
                            float* __restrict__ gdist) {
    __shared__ alignas(16) unsigned short sChi[KT_][CHPAD];
    __shared__ alignas(16) unsigned short sClo[KT_][CHPAD];
    __shared__ alignas(16) unsigned short sHhi[KT_][HPAD];
    __shared__ alignas(16) unsigned short sHlo[KT_][HPAD];
    __shared__ float sA[D_], sr[D_], scb[D_];

    const int bid  = blockIdx.x;
    const int n    = bid >> 3;
    const int k0   = (bid & 7) * KT_;
    const int t    = threadIdx.x;
    const int wid  = t >> 6;
    const int lane = t & 63;
    const int l31  = lane & 31;
    const int koff = (lane >> 5) * 8;

    if (t < D_) {
        sA[t]  = Ag[(size_t)n * D_ + t];
        sr[t]  = z[(size_t)n * D_ + t] - xhat[(size_t)n * D_ + t];
        scb[t] = cp_b[m * D_ + t];
    }
    __syncthreads();

    // ---- C init ----
    {
        const int row  = t >> 3;
        const int dblk = (t & 7) * 16;
        const f32x4* bb4 = (const f32x4*)(Bb + ((size_t)(m * K_ + k0 + row)) * D_ + dblk);
        #pragma unroll
        for (int g = 0; g < 2; ++g) {
            const f32x4 v0 = bb4[g * 2];
            const f32x4 v1 = bb4[g * 2 + 1];
            short8 hs, ls;
            #pragma unroll
            for (int x = 0; x < 8; ++x) {
                const int d = dblk + g * 8 + x;
                const float bv = (x < 4) ? v0[x] : v1[x - 4];
                const float cv = (sA[d] + bv) + scb[d];
                unsigned short ch, cl;
                split2h(cv, ch, cl);
                hs[x] = (short)ch;
                ls[x] = (short)cl;
            }
            *(short8*)&sChi[row][dblk + g * 8] = hs;
            *(short8*)&sClo[row][dblk + g * 8] = ls;
        }
    }
    __syncthreads();

    for (int i = 0; i < NB_; ++i) {
        const int bi = m * NB_ + i;
        const unsigned short* w1h = w1hi + (size_t)bi * H_ * D_;
        const unsigned short* w1l = w1lo + (size_t)bi * H_ * D_;
        const unsigned short* w2h = w2hi + (size_t)bi * D_ * H_;
        const unsigned short* w2l = w2lo + (size_t)bi * D_ * H_;

        // ================= GEMM1: h = relu(C @ W1^T + b1) ==================
        {
            const int j0 = wid * 32 + l31;
            const int j1 = j0 + 128;
            const unsigned short* pj0h = w1h + (size_t)j0 * D_ + koff;
            const unsigned short* pj0l = w1l + (size_t)j0 * D_ + koff;
            const unsigned short* pj1h = w1h + (size_t)j1 * D_ + koff;
            const unsigned short* pj1l = w1l + (size_t)j1 * D_ + koff;

            half8 wA[16], wB[16];
            // batch-issue all j0 weights (16 x b128, latency amortized)
            #pragma unroll
            for (int kt = 0; kt < 8; ++kt) {
                wA[2 * kt]     = *(const half8*)(pj0h + kt * 16);
                wA[2 * kt + 1] = *(const half8*)(pj0l + kt * 16);
            }
            f32x16 acc = zero16();
            #pragma unroll
            for (int kt = 0; kt < 4; ++kt) {
                half8 ah = *(const half8*)&sChi[l31][kt * 16 + koff];
                half8 al = *(const half8*)&sClo[l31][kt * 16 + koff];
                acc = __builtin_amdgcn_mfma_f32_32x32x16_f16(ah, wA[2 * kt], acc, 0, 0, 0);
                acc = __builtin_amdgcn_mfma_f32_32x32x16_f16(ah, wA[2 * kt + 1], acc, 0, 0, 0);
                acc = __builtin_amdgcn_mfma_f32_32x32x16_f16(al, wA[2 * kt], acc, 0, 0, 0);
            }
            // issue j1 weights now; latency hides under remaining MFMAs+epilogue
            #pragma unroll
            for (int kt = 0; kt < 8; ++kt) {
                wB[2 * kt]     = *(const half8*)(pj1h + kt * 16);
                wB[2 * kt + 1] = *(const half8*)(pj1l + kt * 16);
            }
            #pragma unroll
            for (int kt = 4; kt < 8; ++kt) {
                half8 ah = *(const half8*)&sChi[l31][kt * 16 + koff];
                half8 al = *(const half8*)&sClo[l31][kt * 16 + koff];
                acc = __builtin_amdgcn_mfma_f32_32x32x16_f16(ah, wA[2 * kt], acc, 0, 0, 0);
                acc = __builtin_amdgcn_mfma_f32_32x32x16_f16(ah, wA[2 * kt + 1], acc, 0, 0, 0);
                acc = __builtin_amdgcn_mfma_f32_32x32x16_f16(al, wA[2 * kt], acc, 0, 0, 0);
            }
            // epilogue j0
            {
                const float b1A = b1[(size_t)bi * H_ + j0];
                #pragma unroll
                for (int reg = 0; reg < 16; ++reg) {
                    const int krow = (reg & 3) + 8 * (reg >> 2) + 4 * (lane >> 5);
                    const float hA = fmaxf(acc[reg] + b1A, 0.0f);
                    unsigned short hh, hl;
                    split2h(hA, hh, hl);
                    sHhi[krow][j0] = hh;
                    sHlo[krow][j0] = hl;
                }
            }
            // MFMA j1
            acc = zero16();
            #pragma unroll
            for (int kt = 0; kt < 8; ++kt) {
                half8 ah = *(const half8*)&sChi[l31][kt * 16 + koff];
                half8 al = *(const half8*)&sClo[l31][kt * 16 + koff];
                acc = __builtin_amdgcn_mfma_f32_32x32x16_f16(ah, wB[2 * kt], acc, 0, 0, 0);
                acc = __builtin_amdgcn_mfma_f32_32x32x16_f16(ah, wB[2 * kt + 1], acc, 0, 0, 0);
                acc = __builtin_amdgcn_mfma_f32_32x32x16_f16(al, wB[2 * kt], acc, 0, 0, 0);
            }
            // epilogue j1
            {
                const float b1B = b1[(size_t)bi * H_ + j1];
                #pragma unroll
                for (int reg = 0; reg < 16; ++reg) {
                    const int krow = (reg & 3) + 8 * (reg >> 2) + 4 * (lane >> 5);
                    const float hB = fmaxf(acc[reg] + b1B, 0.0f);
                    unsigned short hh, hl;
                    split2h(hB, hh, hl);
                    sHhi[krow][j1] = hh;
                    sHlo[krow][j1] = hl;
                }
            }
        }
        __syncthreads();

        // ================= GEMM2: C = (C + h @ W2^T) + b2 ==================
        {
            const int d = wid * 32 + l31;
            const unsigned short* pdh = w2h + (size_t)d * H_ + koff;
            const unsigned short* pdl = w2l + (size_t)d * H_ + koff;

            half8 wA[16], wB[16];
            #pragma unroll
            for (int s = 0; s < 8; ++s) {
                wA[2 * s]     = *(const half8*)(pdh + s * 16);
                wA[2 * s + 1] = *(const half8*)(pdl + s * 16);
            }
            f32x16 acc0 = zero16(), acc1 = zero16();
            #pragma unroll
            for (int s = 0; s < 4; ++s) {
                half8 hh = *(const half8*)&sHhi[l31][s * 16 + koff];
                half8 hl = *(const half8*)&sHlo[l31][s * 16 + koff];
                acc0 = __builtin_amdgcn_mfma_f32_32x32x16_f16(hh, wA[2 * s], acc0, 0, 0, 0);
                acc0 = __builtin_amdgcn_mfma_f32_32x32x16_f16(hh, wA[2 * s + 1], acc0, 0, 0, 0);
                acc0 = __builtin_amdgcn_mfma_f32_32x32x16_f16(hl, wA[2 * s], acc0, 0, 0, 0);
            }
            #pragma unroll
            for (int s = 0; s < 8; ++s) {
                wB[2 * s]     = *(const half8*)(pdh + (s + 8) * 16);
                wB[2 * s + 1] = *(const half8*)(pdl + (s + 8) * 16);
            }
            #pragma unroll
            for (int s = 4; s < 8; ++s) {
                half8 hh = *(const half8*)&sHhi[l31][s * 16 + koff];
                half8 hl = *(const half8*)&sHlo[l31][s * 16 + koff];
                acc0 = __builtin_amdgcn_mfma_f32_32x32x16_f16(hh, wA[2 * s], acc0, 0, 0, 0);
                acc0 = __builtin_amdgcn_mfma_f32_32x32x16_f16(hh, wA[2 * s + 1], acc0, 0, 0, 0);
                acc0 = __builtin_amdgcn_mfma_f32_32x32x16_f16(hl, wA[2 * s], acc0, 0, 0, 0);
            }
            #pragma unroll
            for (int s = 0; s < 8; ++s) {
                half8 hh = *(const half8*)&sHhi[l31][(s + 8) * 16 + koff];
                half8 hl = *(const half8*)&sHlo[l31][(s + 8) * 16 + koff];
                acc1 = __builtin_amdgcn_mfma_f32_32x32x16_f16(hh, wB[2 * s], acc1, 0, 0, 0);
                acc1 = __builtin_amdgcn_mfma_f32_32x32x16_f16(hh, wB[2 * s + 1], acc1, 0, 0, 0);
                acc1 = __builtin_amdgcn_mfma_f32_32x32x16_f16(hl, wB[2 * s], acc1, 0, 0, 0);
            }
            const float b2v = b2[(size_t)bi * D_ + d];
            #pragma unroll
            for (int reg = 0; reg < 16; ++reg) {
                const int krow = (reg & 3) + 8 * (reg >> 2) + 4 * (lane >> 5);
                const float cvo = s2f(sChi[krow][d]) + s2f(sClo[krow][d]);
                const float cv  = (cvo + (acc0[reg] + acc1[reg])) + b2v;
                unsigned short ch, cl;
                split2h(cv, ch, cl);
                sChi[krow][d] = ch;
                sClo[krow][d] = cl;
            }
        }
        __syncthreads();
    }

    // ---- fast dists ----
    if (t < 128) {
        const int row = t >> 2, seg = t & 3;
        float qa = 0.f;
        #pragma unroll
        for (int dd = 0; dd < 32; ++dd) {
            const int d = seg * 32 + dd;
            const float cv = s2f(sChi[row][d]) + s2f(sClo[row][d]);
            const float e = sr[d] - cv;
            qa = fmaf(e, e, qa);
        }
        qa += __shfl_xor(qa, 1);
        qa += __shfl_xor(qa, 2);
        if (seg == 0) gdist[(size_t)n * K_ + k0 + row] = qa;
    }
}

// ---------------------------------------------------------------------------
// refine kernel (unchanged, exact f64 semantics)
// ---------------------------------------------------------------------------
__launch_bounds__(256, 4)
__global__ void refine_kernel(const int m,
                              const float* __restrict__ z,
                              const float* __restrict__ cp_w,
                              const float* __restrict__ cp_b,
                              const float* __restrict__ w1,
                              const float* __restrict__ b1,
                              const float* __restrict__ w2,
                              const float* __restrict__ b2,
                              const float* __restrict__ Bb,
                              const float* __restrict__ gdist,
                              float* __restrict__ xhat,
                              float* __restrict__ Ag,
                              float* __restrict__ out0,
                              float* __restrict__ out1,
                              float* __restrict__ out2,
                              float* __restrict__ out3) {
    __shared__ float sxhat[D_], sA[D_], sr[D_], scb[D_], scsel[D_], sE[D_];
    __shared__ float shrow[H_];
    __shared__ float sdist[K_];
    __shared__ int   sflag[K_];
    __shared__ double sdd[2];
    __shared__ float smin, sbest;
    __shared__ int   sbidx, supd;

    const int n = blockIdx.x;
    const int t = threadIdx.x;

    if (t < D_) {
        const float xh = xhat[(size_t)n * D_ + t];
        sxhat[t] = xh;
        sA[t]    = Ag[(size_t)n * D_ + t];
        scb[t]   = cp_b[m * D_ + t];
        const float zv = z[(size_t)n * D_ + t];
        const float rv = zv - xh;
        sr[t] = rv;
        out2[((size_t)m * N_ + n) * D_ + t] = rv;
    }
    sdist[t] = gdist[(size_t)n * K_ + t];
    __syncthreads();

    if (t < 64) {
        float bv = 1e30f; int bx = 0;
        #pragma unroll
        for (int u = 0; u < 4; ++u) {
            const int idx = t * 4 + u;
            const float v = sdist[idx];
            if (v < bv) { bv = v; bx = idx; }
        }
        #pragma unroll
        for (int s = 1; s < 64; s <<= 1) {
            const float ov = __shfl_xor(bv, s);
            const int   ox = __shfl_xor(bx, s);
            if (ov < bv || (ov == bv && ox < bx)) { bv = ov; bx = ox; }
        }
        if (t == 0) smin = bv;
    }
    __syncthreads();
    sflag[t] = (sdist[t] <= smin + EPS_) ? 1 : 0;
    if (t == 0) { sbest = 1e30f; sbidx = 0; }
    __syncthreads();

    for (int k = 0; k < K_; ++k) {
        if (!sflag[k]) continue;
        if (t < D_)
            sE[t] = (sA[t] + Bb[((size_t)(m * K_ + k)) * D_ + t]) + scb[t];
        __syncthreads();
        for (int i = 0; i < NB_; ++i) {
            const int bi = m * NB_ + i;
            {
                const f32x4* wp = (const f32x4*)(w1 + ((size_t)bi * H_ + t) * D_);
                double h0 = 0, h1 = 0, h2 = 0, h3 = 0;
                #pragma unroll 8
                for (int u = 0; u < 32; ++u) {
                    f32x4 wv = wp[u];
                    h0 += (double)(sE[u * 4 + 0] * wv[0]);
                    h1 += (double)(sE[u * 4 + 1] * wv[1]);
                    h2 += (double)(sE[u * 4 + 2] * wv[2]);
                    h3 += (double)(sE[u * 4 + 3] * wv[3]);
                }
                const float hv = (float)((h0 + h1) + (h2 + h3)) + b1[(size_t)bi * H_ + t];
                shrow[t] = fmaxf(hv, 0.0f);
            }
            __syncthreads();
            if (t < D_) {
                const f32x4* wp = (const f32x4*)(w2 + ((size_t)bi * D_ + t) * H_);
                double s0 = 0, s1 = 0, s2 = 0, s3 = 0;
                #pragma unroll 8
                for (int u = 0; u < 64; ++u) {
                    f32x4 wv = wp[u];
                    s0 += (double)(shrow[u * 4 + 0] * wv[0]);
                    s1 += (double)(shrow[u * 4 + 1] * wv[1]);
                    s2 += (double)(shrow[u * 4 + 2] * wv[2]);
                    s3 += (double)(shrow[u * 4 + 3] * wv[3]);
                }
                sE[t] = (sE[t] + (float)((s0 + s1) + (s2 + s3))) + b2[(size_t)bi * D_ + t];
            }
            __syncthreads();
        }
        {
            double dp = 0.0;
            if (t < D_) {
                const float e = sr[t] - sE[t];
                const float e2 = e * e;
                dp = (double)e2;
                #pragma unroll
                for (int s = 1; s < 64; s <<= 1) dp += __shfl_xor(dp, s);
                if ((t & 63) == 0) sdd[t >> 6] = dp;
            }
        }
        __syncthreads();
        if (t == 0) {
            const float df = (float)(sdd[0] + sdd[1]);
            if (df < sbest) { sbest = df; sbidx = k; supd = 1; }
            else supd = 0;
        }
        __syncthreads();
        if (supd && t < D_) scsel[t] = sE[t];
        __syncthreads();
    }

    if (t == 0) out1[(size_t)n * M_ + m] = (float)sbidx;

    if (t < D_) {
        const float cs = scsel[t];
        out3[((size_t)m * N_ + n) * D_ + t] = cs;
        const float xnew = sxhat[t] + cs;
        xhat[(size_t)n * D_ + t] = xnew;
        sxhat[t] = xnew;
        if (m == M_ - 1) {
            const float zv = z[(size_t)n * D_ + t];
            out0[(size_t)n * D_ + t] = zv + (xnew - zv);
        }
    }
    __syncthreads();

    if (m < M_ - 1 && t < D_) {
        const f32x4* wp = (const f32x4*)(cp_w + ((size_t)((m + 1) * D_ + t)) * (2 * D_));
        double a0 = 0, a1 = 0, a2 = 0, a3 = 0;
        #pragma unroll 8
        for (int u = 0; u < 32; ++u) {
            f32x4 wv = wp[u];
            a0 += (double)(sxhat[u * 4 + 0] * wv[0]);
            a1 += (double)(sxhat[u * 4 + 1] * wv[1]);
            a2 += (double)(sxhat[u * 4 + 2] * wv[2]);
            a3 += (double)(sxhat[u * 4 + 3] * wv[3]);
        }
        Ag[(size_t)n * D_ + t] = (float)((a0 + a1) + (a2 + a3));
    }
}

extern "C" void kernel_launch(void* const* d_in, const int* in_sizes, int n_in,
                              void* d_out, int out_size, void* d_ws, size_t ws_size,
                              hipStream_t stream) {
    const float* z       = (const float*)d_in[0];
    const float* base_cb = (const float*)d_in[1];
    const float* cp_w    = (const float*)d_in[2];
    const float* cp_b    = (const float*)d_in[3];
    const float* w1      = (const float*)d_in[4];
    const float* b1      = (const float*)d_in[5];
    const float* w2      = (const float*)d_in[6];
    const float* b2      = (const float*)d_in[7];

    float* out  = (float*)d_out;
    float* out0 = out;
    float* out1 = out0 + (size_t)N_ * D_;
    float* out2 = out1 + (size_t)N_ * M_;
    float* out3 = out2 + (size_t)M_ * N_ * D_;

    char* ws = (char*)d_ws;
    float*          Bb    = (float*)(ws + 0);
    unsigned short* w1hi  = (unsigned short*)(ws + 524288);
    unsigned short* w1lo  = (unsigned short*)(ws + 1048576);
    unsigned short* w2hi  = (unsigned short*)(ws + 1572864);
    unsigned short* w2lo  = (unsigned short*)(ws + 2097152);
    float*          xhat  = (float*)(ws + 2621440);
    float*          Ag    = (float*)(ws + 3145728);
    float*          gdist = (float*)(ws + 3670016);

    hipLaunchKernelGGL(precompute_Bb, dim3(M_ * K_), dim3(D_), 0, stream,
                       base_cb, cp_w, Bb);
    hipLaunchKernelGGL(convert_w, dim3(1024), dim3(256), 0, stream,
                       w1, w2, w1hi, w1lo, w2hi, w2lo);
    hipLaunchKernelGGL(init_state, dim3(512), dim3(256), 0, stream, xhat, Ag);

    for (int m = 0; m < M_; ++m) {
        hipLaunchKernelGGL(dist_kernel, dim3(N_ * 8), dim3(256), 0, stream,
                           m, z, cp_b, xhat, Ag, Bb,
                           w1hi, w1lo, w2hi, w2lo, b1, b2, gdist);
        hipLaunchKernelGGL(refine_kernel, dim3(N_), dim3(256), 0, stream,
                           m, z, cp_w, cp_b, w1, b1, w2, b2, Bb, gdist,
                           xhat, Ag, out0, out1, out2, out3);
    }
}

// Round 9
// 1387.908 us; speedup vs baseline: 2.0158x; 1.6600x over previous
//
#include <hip/hip_runtime.h>

#define N_ 1024
#define D_ 128
#define K_ 256
#define M_ 4
#define H_ 256
#define NB_ 2
#define KT_ 32
#define EPS_ 0.02f
#define CHPAD 136
#define HPAD  264

typedef _Float16 half8 __attribute__((ext_vector_type(8)));
typedef __attribute__((ext_vector_type(8))) short short8;
typedef __attribute__((ext_vector_type(4))) float f32x4;
typedef __attribute__((ext_vector_type(16))) float f32x16;

__device__ inline float s2f(unsigned short s) {
    return (float)__builtin_bit_cast(_Float16, s);
}
__device__ inline void split2h(float x, unsigned short& hi, unsigned short& lo) {
    _Float16 h = (_Float16)x;
    _Float16 l = (_Float16)(x - (float)h);
    hi = __builtin_bit_cast(unsigned short, h);
    lo = __builtin_bit_cast(unsigned short, l);
}
__device__ inline f32x16 zero16() {
    f32x16 v;
    #pragma unroll
    for (int i = 0; i < 16; ++i) v[i] = 0.0f;
    return v;
}

// ---------------------------------------------------------------------------
__global__ void precompute_Bb(const float* __restrict__ base_cb,
                              const float* __restrict__ cp_w,
                              float* __restrict__ Bb) {
    const int mk = blockIdx.x;
    const int m  = mk >> 8;
    const int d  = threadIdx.x;
    const float* cb = base_cb + (size_t)mk * D_;
    const float* wc = cp_w + ((size_t)(m * D_ + d)) * (2 * D_) + D_;
    double a0 = 0, a1 = 0, a2 = 0, a3 = 0;
    #pragma unroll
    for (int dp = 0; dp < D_; dp += 4) {
        a0 += (double)(cb[dp + 0] * wc[dp + 0]);
        a1 += (double)(cb[dp + 1] * wc[dp + 1]);
        a2 += (double)(cb[dp + 2] * wc[dp + 2]);
        a3 += (double)(cb[dp + 3] * wc[dp + 3]);
    }
    Bb[(size_t)mk * D_ + d] = (float)((a0 + a1) + (a2 + a3));
}

// ---------------------------------------------------------------------------
// Pack weights into wave-coalesced fragment order.
// w1pk index: ((((bi*8 + jblk)*8 + kt)*32 + j32)*2 + sel)*8 + e
//   source:   w1[bi][ j = jblk*32+j32 ][ d = kt*16 + sel*8 + e ]
// w2pk index: ((((bi*4 + dblk)*16 + s)*32 + d32)*2 + sel)*8 + e
//   source:   w2[bi][ d = dblk*32+d32 ][ h = s*16 + sel*8 + e ]
// ---------------------------------------------------------------------------
__global__ void convert_w(const float* __restrict__ w1,
                          const float* __restrict__ w2,
                          unsigned short* __restrict__ w1h,
                          unsigned short* __restrict__ w1l,
                          unsigned short* __restrict__ w2h,
                          unsigned short* __restrict__ w2l) {
    const int i = blockIdx.x * blockDim.x + threadIdx.x;  // 0..262143
    {
        const int e    = i & 7;
        const int sel  = (i >> 3) & 1;
        const int j32  = (i >> 4) & 31;
        const int kt   = (i >> 9) & 7;
        const int jblk = (i >> 12) & 7;
        const int bi   = i >> 15;
        const int j = jblk * 32 + j32;
        const int d = kt * 16 + sel * 8 + e;
        const float v = w1[((size_t)(bi * H_ + j)) * D_ + d];
        unsigned short h, l;
        split2h(v, h, l);
        w1h[i] = h; w1l[i] = l;
    }
    {
        const int e    = i & 7;
        const int sel  = (i >> 3) & 1;
        const int d32  = (i >> 4) & 31;
        const int s    = (i >> 9) & 15;
        const int dblk = (i >> 13) & 3;
        const int bi   = i >> 15;
        const int d = dblk * 32 + d32;
        const int hc = s * 16 + sel * 8 + e;
        const float v = w2[((size_t)(bi * D_ + d)) * H_ + hc];
        unsigned short h, l;
        split2h(v, h, l);
        w2h[i] = h; w2l[i] = l;
    }
}

__global__ void init_state(float* __restrict__ xhat, float* __restrict__ Ag) {
    const int i = blockIdx.x * blockDim.x + threadIdx.x;
    xhat[i] = 0.0f;
    Ag[i] = 0.0f;
}

// ---------------------------------------------------------------------------
// dist kernel: block (n, kt) -> fast dists for 32 codewords.
// Weight loads fully coalesced (1 KB contiguous per wave instruction).
// ---------------------------------------------------------------------------
__launch_bounds__(256, 3)
__global__ void dist_kernel(const int m,
                            const float* __restrict__ z,
                            const float* __restrict__ cp_b,
                            const float* __restrict__ xhat,
                            const float* __restrict__ Ag,
                            const float* __restrict__ Bb,
                            const unsigned short* __restrict__ w1hpk,
                            const unsigned short* __restrict__ w1lpk,
                            const unsigned short* __restrict__ w2hpk,
                            const unsigned short* __restrict__ w2lpk,
                            const float* __restrict__ b1,
                            const float* __restrict__ b2,
                            float* __restrict__ gdist) {
    __shared__ alignas(16) unsigned short sChi[KT_][CHPAD];
    __shared__ alignas(16) unsigned short sClo[KT_][CHPAD];
    __shared__ alignas(16) unsigned short sHhi[KT_][HPAD];
    __shared__ alignas(16) unsigned short sHlo[KT_][HPAD];
    __shared__ float sA[D_], sr[D_], scb[D_];

    const int bid  = blockIdx.x;
    const int n    = bid >> 3;
    const int k0   = (bid & 7) * KT_;
    const int t    = threadIdx.x;
    const int wid  = t >> 6;
    const int lane = t & 63;
    const int l31  = lane & 31;
    const int koff = (lane >> 5) * 8;
    const int loff = (l31 * 2 + (lane >> 5)) * 8;   // coalesced lane offset

    if (t < D_) {
        sA[t]  = Ag[(size_t)n * D_ + t];
        sr[t]  = z[(size_t)n * D_ + t] - xhat[(size_t)n * D_ + t];
        scb[t] = cp_b[m * D_ + t];
    }
    __syncthreads();

    // ---- C init ----
    {
        const int row  = t >> 3;
        const int dblk = (t & 7) * 16;
        const f32x4* bb4 = (const f32x4*)(Bb + ((size_t)(m * K_ + k0 + row)) * D_ + dblk);
        #pragma unroll
        for (int g = 0; g < 2; ++g) {
            const f32x4 v0 = bb4[g * 2];
            const f32x4 v1 = bb4[g * 2 + 1];
            short8 hs, ls;
            #pragma unroll
            for (int x = 0; x < 8; ++x) {
                const int d = dblk + g * 8 + x;
                const float bv = (x < 4) ? v0[x] : v1[x - 4];
                const float cv = (sA[d] + bv) + scb[d];
                unsigned short ch, cl;
                split2h(cv, ch, cl);
                hs[x] = (short)ch;
                ls[x] = (short)cl;
            }
            *(short8*)&sChi[row][dblk + g * 8] = hs;
            *(short8*)&sClo[row][dblk + g * 8] = ls;
        }
    }
    __syncthreads();

    for (int i = 0; i < NB_; ++i) {
        const int bi = m * NB_ + i;

        // ================= GEMM1: h = relu(C @ W1^T + b1) ==================
        {
            const int j0 = wid * 32 + l31;
            const int j1 = j0 + 128;
            // packed bases: jblkA = wid, jblkB = wid + 4; 512 halfs per kt chunk
            const unsigned short* pAh = w1hpk + ((size_t)(bi * 8 + wid) * 8) * 512 + loff;
            const unsigned short* pAl = w1lpk + ((size_t)(bi * 8 + wid) * 8) * 512 + loff;
            const unsigned short* pBh = w1hpk + ((size_t)(bi * 8 + wid + 4) * 8) * 512 + loff;
            const unsigned short* pBl = w1lpk + ((size_t)(bi * 8 + wid + 4) * 8) * 512 + loff;

            half8 wA[16], wB[16];
            #pragma unroll
            for (int kt = 0; kt < 8; ++kt) {
                wA[2 * kt]     = *(const half8*)(pAh + kt * 512);
                wA[2 * kt + 1] = *(const half8*)(pAl + kt * 512);
            }
            f32x16 acc = zero16();
            #pragma unroll
            for (int kt = 0; kt < 4; ++kt) {
                half8 ah = *(const half8*)&sChi[l31][kt * 16 + koff];
                half8 al = *(const half8*)&sClo[l31][kt * 16 + koff];
                acc = __builtin_amdgcn_mfma_f32_32x32x16_f16(ah, wA[2 * kt], acc, 0, 0, 0);
                acc = __builtin_amdgcn_mfma_f32_32x32x16_f16(ah, wA[2 * kt + 1], acc, 0, 0, 0);
                acc = __builtin_amdgcn_mfma_f32_32x32x16_f16(al, wA[2 * kt], acc, 0, 0, 0);
            }
            #pragma unroll
            for (int kt = 0; kt < 8; ++kt) {
                wB[2 * kt]     = *(const half8*)(pBh + kt * 512);
                wB[2 * kt + 1] = *(const half8*)(pBl + kt * 512);
            }
            #pragma unroll
            for (int kt = 4; kt < 8; ++kt) {
                half8 ah = *(const half8*)&sChi[l31][kt * 16 + koff];
                half8 al = *(const half8*)&sClo[l31][kt * 16 + koff];
                acc = __builtin_amdgcn_mfma_f32_32x32x16_f16(ah, wA[2 * kt], acc, 0, 0, 0);
                acc = __builtin_amdgcn_mfma_f32_32x32x16_f16(ah, wA[2 * kt + 1], acc, 0, 0, 0);
                acc = __builtin_amdgcn_mfma_f32_32x32x16_f16(al, wA[2 * kt], acc, 0, 0, 0);
            }
            {
                const float b1A = b1[(size_t)bi * H_ + j0];
                #pragma unroll
                for (int reg = 0; reg < 16; ++reg) {
                    const int krow = (reg & 3) + 8 * (reg >> 2) + 4 * (lane >> 5);
                    const float hA = fmaxf(acc[reg] + b1A, 0.0f);
                    unsigned short hh, hl;
                    split2h(hA, hh, hl);
                    sHhi[krow][j0] = hh;
                    sHlo[krow][j0] = hl;
                }
            }
            acc = zero16();
            #pragma unroll
            for (int kt = 0; kt < 8; ++kt) {
                half8 ah = *(const half8*)&sChi[l31][kt * 16 + koff];
                half8 al = *(const half8*)&sClo[l31][kt * 16 + koff];
                acc = __builtin_amdgcn_mfma_f32_32x32x16_f16(ah, wB[2 * kt], acc, 0, 0, 0);
                acc = __builtin_amdgcn_mfma_f32_32x32x16_f16(ah, wB[2 * kt + 1], acc, 0, 0, 0);
                acc = __builtin_amdgcn_mfma_f32_32x32x16_f16(al, wB[2 * kt], acc, 0, 0, 0);
            }
            {
                const float b1B = b1[(size_t)bi * H_ + j1];
                #pragma unroll
                for (int reg = 0; reg < 16; ++reg) {
                    const int krow = (reg & 3) + 8 * (reg >> 2) + 4 * (lane >> 5);
                    const float hB = fmaxf(acc[reg] + b1B, 0.0f);
                    unsigned short hh, hl;
                    split2h(hB, hh, hl);
                    sHhi[krow][j1] = hh;
                    sHlo[krow][j1] = hl;
                }
            }
        }
        __syncthreads();

        // ================= GEMM2: C = (C + h @ W2^T) + b2 ==================
        {
            const int d = wid * 32 + l31;
            // packed base: dblk = wid; 512 halfs per s chunk
            const unsigned short* pdh = w2hpk + ((size_t)(bi * 4 + wid) * 16) * 512 + loff;
            const unsigned short* pdl = w2lpk + ((size_t)(bi * 4 + wid) * 16) * 512 + loff;

            half8 wA[16], wB[16];
            #pragma unroll
            for (int s = 0; s < 8; ++s) {
                wA[2 * s]     = *(const half8*)(pdh + s * 512);
                wA[2 * s + 1] = *(const half8*)(pdl + s * 512);
            }
            f32x16 acc0 = zero16(), acc1 = zero16();
            #pragma unroll
            for (int s = 0; s < 4; ++s) {
                half8 hh = *(const half8*)&sHhi[l31][s * 16 + koff];
                half8 hl = *(const half8*)&sHlo[l31][s * 16 + koff];
                acc0 = __builtin_amdgcn_mfma_f32_32x32x16_f16(hh, wA[2 * s], acc0, 0, 0, 0);
                acc0 = __builtin_amdgcn_mfma_f32_32x32x16_f16(hh, wA[2 * s + 1], acc0, 0, 0, 0);
                acc0 = __builtin_amdgcn_mfma_f32_32x32x16_f16(hl, wA[2 * s], acc0, 0, 0, 0);
            }
            #pragma unroll
            for (int s = 0; s < 8; ++s) {
                wB[2 * s]     = *(const half8*)(pdh + (s + 8) * 512);
                wB[2 * s + 1] = *(const half8*)(pdl + (s + 8) * 512);
            }
            #pragma unroll
            for (int s = 4; s < 8; ++s) {
                half8 hh = *(const half8*)&sHhi[l31][s * 16 + koff];
                half8 hl = *(const half8*)&sHlo[l31][s * 16 + koff];
                acc0 = __builtin_amdgcn_mfma_f32_32x32x16_f16(hh, wA[2 * s], acc0, 0, 0, 0);
                acc0 = __builtin_amdgcn_mfma_f32_32x32x16_f16(hh, wA[2 * s + 1], acc0, 0, 0, 0);
                acc0 = __builtin_amdgcn_mfma_f32_32x32x16_f16(hl, wA[2 * s], acc0, 0, 0, 0);
            }
            #pragma unroll
            for (int s = 0; s < 8; ++s) {
                half8 hh = *(const half8*)&sHhi[l31][(s + 8) * 16 + koff];
                half8 hl = *(const half8*)&sHlo[l31][(s + 8) * 16 + koff];
                acc1 = __builtin_amdgcn_mfma_f32_32x32x16_f16(hh, wB[2 * s], acc1, 0, 0, 0);
                acc1 = __builtin_amdgcn_mfma_f32_32x32x16_f16(hh, wB[2 * s + 1], acc1, 0, 0, 0);
                acc1 = __builtin_amdgcn_mfma_f32_32x32x16_f16(hl, wB[2 * s], acc1, 0, 0, 0);
            }
            const float b2v = b2[(size_t)bi * D_ + d];
            #pragma unroll
            for (int reg = 0; reg < 16; ++reg) {
                const int krow = (reg & 3) + 8 * (reg >> 2) + 4 * (lane >> 5);
                const float cvo = s2f(sChi[krow][d]) + s2f(sClo[krow][d]);
                const float cv  = (cvo + (acc0[reg] + acc1[reg])) + b2v;
                unsigned short ch, cl;
                split2h(cv, ch, cl);
                sChi[krow][d] = ch;
                sClo[krow][d] = cl;
            }
        }
        __syncthreads();
    }

    // ---- fast dists ----
    if (t < 128) {
        const int row = t >> 2, seg = t & 3;
        float qa = 0.f;
        #pragma unroll
        for (int dd = 0; dd < 32; ++dd) {
            const int d = seg * 32 + dd;
            const float cv = s2f(sChi[row][d]) + s2f(sClo[row][d]);
            const float e = sr[d] - cv;
            qa = fmaf(e, e, qa);
        }
        qa += __shfl_xor(qa, 1);
        qa += __shfl_xor(qa, 2);
        if (seg == 0) gdist[(size_t)n * K_ + k0 + row] = qa;
    }
}

// ---------------------------------------------------------------------------
// refine kernel (unchanged, exact f64 semantics)
// ---------------------------------------------------------------------------
__launch_bounds__(256, 4)
__global__ void refine_kernel(const int m,
                              const float* __restrict__ z,
                              const float* __restrict__ cp_w,
                              const float* __restrict__ cp_b,
                              const float* __restrict__ w1,
                              const float* __restrict__ b1,
                              const float* __restrict__ w2,
                              const float* __restrict__ b2,
                              const float* __restrict__ Bb,
                              const float* __restrict__ gdist,
                              float* __restrict__ xhat,
                              float* __restrict__ Ag,
                              float* __restrict__ out0,
                              float* __restrict__ out1,
                              float* __restrict__ out2,
                              float* __restrict__ out3) {
    __shared__ float sxhat[D_], sA[D_], sr[D_], scb[D_], scsel[D_], sE[D_];
    __shared__ float shrow[H_];
    __shared__ float sdist[K_];
    __shared__ int   sflag[K_];
    __shared__ double sdd[2];
    __shared__ float smin, sbest;
    __shared__ int   sbidx, supd;

    const int n = blockIdx.x;
    const int t = threadIdx.x;

    if (t < D_) {
        const float xh = xhat[(size_t)n * D_ + t];
        sxhat[t] = xh;
        sA[t]    = Ag[(size_t)n * D_ + t];
        scb[t]   = cp_b[m * D_ + t];
        const float zv = z[(size_t)n * D_ + t];
        const float rv = zv - xh;
        sr[t] = rv;
        out2[((size_t)m * N_ + n) * D_ + t] = rv;
    }
    sdist[t] = gdist[(size_t)n * K_ + t];
    __syncthreads();

    if (t < 64) {
        float bv = 1e30f; int bx = 0;
        #pragma unroll
        for (int u = 0; u < 4; ++u) {
            const int idx = t * 4 + u;
            const float v = sdist[idx];
            if (v < bv) { bv = v; bx = idx; }
        }
        #pragma unroll
        for (int s = 1; s < 64; s <<= 1) {
            const float ov = __shfl_xor(bv, s);
            const int   ox = __shfl_xor(bx, s);
            if (ov < bv || (ov == bv && ox < bx)) { bv = ov; bx = ox; }
        }
        if (t == 0) smin = bv;
    }
    __syncthreads();
    sflag[t] = (sdist[t] <= smin + EPS_) ? 1 : 0;
    if (t == 0) { sbest = 1e30f; sbidx = 0; }
    __syncthreads();

    for (int k = 0; k < K_; ++k) {
        if (!sflag[k]) continue;
        if (t < D_)
            sE[t] = (sA[t] + Bb[((size_t)(m * K_ + k)) * D_ + t]) + scb[t];
        __syncthreads();
        for (int i = 0; i < NB_; ++i) {
            const int bi = m * NB_ + i;
            {
                const f32x4* wp = (const f32x4*)(w1 + ((size_t)bi * H_ + t) * D_);
                double h0 = 0, h1 = 0, h2 = 0, h3 = 0;
                #pragma unroll 8
                for (int u = 0; u < 32; ++u) {
                    f32x4 wv = wp[u];
                    h0 += (double)(sE[u * 4 + 0] * wv[0]);
                    h1 += (double)(sE[u * 4 + 1] * wv[1]);
                    h2 += (double)(sE[u * 4 + 2] * wv[2]);
                    h3 += (double)(sE[u * 4 + 3] * wv[3]);
                }
                const float hv = (float)((h0 + h1) + (h2 + h3)) + b1[(size_t)bi * H_ + t];
                shrow[t] = fmaxf(hv, 0.0f);
            }
            __syncthreads();
            if (t < D_) {
                const f32x4* wp = (const f32x4*)(w2 + ((size_t)bi * D_ + t) * H_);
                double s0 = 0, s1 = 0, s2 = 0, s3 = 0;
                #pragma unroll 8
                for (int u = 0; u < 64; ++u) {
                    f32x4 wv = wp[u];
                    s0 += (double)(shrow[u * 4 + 0] * wv[0]);
                    s1 += (double)(shrow[u * 4 + 1] * wv[1]);
                    s2 += (double)(shrow[u * 4 + 2] * wv[2]);
                    s3 += (double)(shrow[u * 4 + 3] * wv[3]);
                }
                sE[t] = (sE[t] + (float)((s0 + s1) + (s2 + s3))) + b2[(size_t)bi * D_ + t];
            }
            __syncthreads();
        }
        {
            double dp = 0.0;
            if (t < D_) {
                const float e = sr[t] - sE[t];
                const float e2 = e * e;
                dp = (double)e2;
                #pragma unroll
                for (int s = 1; s < 64; s <<= 1) dp += __shfl_xor(dp, s);
                if ((t & 63) == 0) sdd[t >> 6] = dp;
            }
        }
        __syncthreads();
        if (t == 0) {
            const float df = (float)(sdd[0] + sdd[1]);
            if (df < sbest) { sbest = df; sbidx = k; supd = 1; }
            else supd = 0;
        }
        __syncthreads();
        if (supd && t < D_) scsel[t] = sE[t];
        __syncthreads();
    }

    if (t == 0) out1[(size_t)n * M_ + m] = (float)sbidx;

    if (t < D_) {
        const float cs = scsel[t];
        out3[((size_t)m * N_ + n) * D_ + t] = cs;
        const float xnew = sxhat[t] + cs;
        xhat[(size_t)n * D_ + t] = xnew;
        sxhat[t] = xnew;
        if (m == M_ - 1) {
            const float zv = z[(size_t)n * D_ + t];
            out0[(size_t)n * D_ + t] = zv + (xnew - zv);
        }
    }
    __syncthreads();

    if (m < M_ - 1 && t < D_) {
        const f32x4* wp = (const f32x4*)(cp_w + ((size_t)((m + 1) * D_ + t)) * (2 * D_));
        double a0 = 0, a1 = 0, a2 = 0, a3 = 0;
        #pragma unroll 8
        for (int u = 0; u < 32; ++u) {
            f32x4 wv = wp[u];
            a0 += (double)(sxhat[u * 4 + 0] * wv[0]);
            a1 += (double)(sxhat[u * 4 + 1] * wv[1]);
            a2 += (double)(sxhat[u * 4 + 2] * wv[2]);
            a3 += (double)(sxhat[u * 4 + 3] * wv[3]);
        }
        Ag[(size_t)n * D_ + t] = (float)((a0 + a1) + (a2 + a3));
    }
}

extern "C" void kernel_launch(void* const* d_in, const int* in_sizes, int n_in,
                              void* d_out, int out_size, void* d_ws, size_t ws_size,
                              hipStream_t stream) {
    const float* z       = (const float*)d_in[0];
    const float* base_cb = (const float*)d_in[1];
    const float* cp_w    = (const float*)d_in[2];
    const float* cp_b    = (const float*)d_in[3];
    const float* w1      = (const float*)d_in[4];
    const float* b1      = (const float*)d_in[5];
    const float* w2      = (const float*)d_in[6];
    const float* b2      = (const float*)d_in[7];

    float* out  = (float*)d_out;
    float* out0 = out;
    float* out1 = out0 + (size_t)N_ * D_;
    float* out2 = out1 + (size_t)N_ * M_;
    float* out3 = out2 + (size_t)M_ * N_ * D_;

    char* ws = (char*)d_ws;
    float*          Bb    = (float*)(ws + 0);
    unsigned short* w1hpk = (unsigned short*)(ws + 524288);
    unsigned short* w1lpk = (unsigned short*)(ws + 1048576);
    unsigned short* w2hpk = (unsigned short*)(ws + 1572864);
    unsigned short* w2lpk = (unsigned short*)(ws + 2097152);
    float*          xhat  = (float*)(ws + 2621440);
    float*          Ag    = (float*)(ws + 3145728);
    float*          gdist = (float*)(ws + 3670016);

    hipLaunchKernelGGL(precompute_Bb, dim3(M_ * K_), dim3(D_), 0, stream,
                       base_cb, cp_w, Bb);
    hipLaunchKernelGGL(convert_w, dim3(1024), dim3(256), 0, stream,
                       w1, w2, w1hpk, w1lpk, w2hpk, w2lpk);
    hipLaunchKernelGGL(init_state, dim3(512), dim3(256), 0, stream, xhat, Ag);

    for (int m = 0; m < M_; ++m) {
        hipLaunchKernelGGL(dist_kernel, dim3(N_ * 8), dim3(256), 0, stream,
                           m, z, cp_b, xhat, Ag, Bb,
                           w1hpk, w1lpk, w2hpk, w2lpk, b1, b2, gdist);
        hipLaunchKernelGGL(refine_kernel, dim3(N_), dim3(256), 0, stream,
                           m, z, cp_w, cp_b, w1, b1, w2, b2, Bb, gdist,
                           xhat, Ag, out0, out1, out2, out3);
    }
}